// Round 1
// baseline (98.181 us; speedup 1.0000x reference)
//
#include <hip/hip_runtime.h>
#include <math.h>

#define NRAYS 8192

// ---------------- wave-level primitives (wave64) ----------------
__device__ __forceinline__ float wave_scan_prod(float v, int lane) {
#pragma unroll
  for (int off = 1; off < 64; off <<= 1) {
    float n = __shfl_up(v, off, 64);
    if (lane >= off) v *= n;
  }
  return v;
}
__device__ __forceinline__ float wave_scan_sum(float v, int lane) {
#pragma unroll
  for (int off = 1; off < 64; off <<= 1) {
    float n = __shfl_up(v, off, 64);
    if (lane >= off) v += n;
  }
  return v;
}
__device__ __forceinline__ float wave_reduce_sum(float v) {
#pragma unroll
  for (int off = 32; off >= 1; off >>= 1) v += __shfl_xor(v, off, 64);
  return v;
}

// ---------------- density MLP: in=(x,y,z,t) -> 64 relu -> 16 ----------------
// dpk row j (32 floats): [0..3]=Wd1[:,j], [4]=bd1[j], [8..23]=Wd2[j,:]
__device__ __forceinline__ void density_mlp(const float* __restrict__ dpk,
                                            const float* __restrict__ bd2,
                                            float x, float y, float z, float t,
                                            float (&acc)[16]) {
#pragma unroll
  for (int k = 0; k < 16; ++k) acc[k] = bd2[k];
#pragma unroll 4
  for (int j = 0; j < 64; ++j) {
    const float* __restrict__ r = dpk + (j << 5);
    float h = r[4];
    h = fmaf(x, r[0], h);
    h = fmaf(y, r[1], h);
    h = fmaf(z, r[2], h);
    h = fmaf(t, r[3], h);
    h = fmaxf(h, 0.f);
#pragma unroll
    for (int k = 0; k < 16; ++k) acc[k] = fmaf(h, r[8 + k], acc[k]);
  }
}

// ---------------- color MLP: in=(d0,d1,d2,geo[15]) -> 64 relu -> 3 sigmoid --
// cpk row j (32 floats): [0..17]=Wc1[:,j], [18]=bc1[j], [20..22]=Wc2[j,:]
__device__ __forceinline__ void color_mlp(const float* __restrict__ cpk,
                                          const float* __restrict__ bc2,
                                          float d0, float d1, float d2,
                                          const float (&geo)[15], float (&rgb)[3]) {
  float a0 = bc2[0], a1 = bc2[1], a2 = bc2[2];
#pragma unroll 4
  for (int j = 0; j < 64; ++j) {
    const float* __restrict__ r = cpk + (j << 5);
    float h = r[18];
    h = fmaf(d0, r[0], h);
    h = fmaf(d1, r[1], h);
    h = fmaf(d2, r[2], h);
#pragma unroll
    for (int g = 0; g < 15; ++g) h = fmaf(geo[g], r[3 + g], h);
    h = fmaxf(h, 0.f);
    a0 = fmaf(h, r[20], a0);
    a1 = fmaf(h, r[21], a1);
    a2 = fmaf(h, r[22], a2);
  }
  rgb[0] = 1.f / (1.f + expf(-a0));
  rgb[1] = 1.f / (1.f + expf(-a1));
  rgb[2] = 1.f / (1.f + expf(-a2));
}

// ---------------- weight packing prologue ----------------
__global__ void pack_weights(const float* __restrict__ Wd1, const float* __restrict__ bd1,
                             const float* __restrict__ Wd2, const float* __restrict__ Wc1,
                             const float* __restrict__ bc1, const float* __restrict__ Wc2,
                             float* __restrict__ pk) {
  int j = threadIdx.x;  // 64 threads
  float* dr = pk + j * 32;
  dr[0] = Wd1[j];
  dr[1] = Wd1[64 + j];
  dr[2] = Wd1[128 + j];
  dr[3] = Wd1[192 + j];
  dr[4] = bd1[j];
  dr[5] = 0.f; dr[6] = 0.f; dr[7] = 0.f;
#pragma unroll
  for (int k = 0; k < 16; ++k) dr[8 + k] = Wd2[j * 16 + k];
#pragma unroll
  for (int k = 24; k < 32; ++k) dr[k] = 0.f;

  float* cr = pk + 2048 + j * 32;
#pragma unroll
  for (int c = 0; c < 18; ++c) cr[c] = Wc1[c * 64 + j];
  cr[18] = bc1[j];
  cr[19] = 0.f;
  cr[20] = Wc2[j * 3 + 0];
  cr[21] = Wc2[j * 3 + 1];
  cr[22] = Wc2[j * 3 + 2];
#pragma unroll
  for (int k = 23; k < 32; ++k) cr[k] = 0.f;
}

// ---------------- main renderer: one wave per ray, 4 rays per block --------
__global__ __launch_bounds__(256) void nerf_render(
    const float* __restrict__ rays_o, const float* __restrict__ rays_d,
    const float* __restrict__ time_p, const float* __restrict__ bg,
    const float* __restrict__ bd2g, const float* __restrict__ bc2g,
    const float* __restrict__ pk, float* __restrict__ out) {
  __shared__ float s_cz[4][64];    // coarse z
  __shared__ float s_nz[4][64];    // fine z
  __shared__ float s_cdf[4][64];   // cdf[0..62]
  __shared__ float s_mid[4][64];   // bins[0..62]
  __shared__ float s_zs[4][128];   // merged sorted z
  __shared__ float s_ss[4][128];   // merged sorted sigma
  __shared__ float s_ws[4][128];   // merged weights

  const int lane = threadIdx.x & 63;
  const int w = threadIdx.x >> 6;
  const int ray = (blockIdx.x << 2) + w;
  if (ray >= NRAYS) return;

  const float t = time_p[0];
  const float o0 = rays_o[ray * 3 + 0], o1 = rays_o[ray * 3 + 1], o2 = rays_o[ray * 3 + 2];
  const float d0 = rays_d[ray * 3 + 0], d1 = rays_d[ray * 3 + 1], d2 = rays_d[ray * 3 + 2];

  // ---- near / far from aabb [-1,1]^3 ----
  float nearv, farv;
  {
    float i0 = 1.f / ((fabsf(d0) < 1e-9f) ? 1e-9f : d0);
    float i1 = 1.f / ((fabsf(d1) < 1e-9f) ? 1e-9f : d1);
    float i2 = 1.f / ((fabsf(d2) < 1e-9f) ? 1e-9f : d2);
    float a0 = (-1.f - o0) * i0, b0 = (1.f - o0) * i0;
    float a1 = (-1.f - o1) * i1, b1 = (1.f - o1) * i1;
    float a2 = (-1.f - o2) * i2, b2 = (1.f - o2) * i2;
    float tmin = fmaxf(fmaxf(fminf(a0, b0), fminf(a1, b1)), fminf(a2, b2));
    float tmax = fminf(fminf(fmaxf(a0, b0), fmaxf(a1, b1)), fmaxf(a2, b2));
    nearv = fmaxf(tmin, 0.05f);
    farv = (tmax < nearv) ? (nearv + 1e-2f) : tmax;
  }
  const float sd = (farv - nearv) * (1.f / 64.f);  // sample_dist

  const float* dpk = pk;
  const float* cpk = pk + 2048;

  float bd2[16];
#pragma unroll
  for (int k = 0; k < 16; ++k) bd2[k] = bd2g[k];
  float bc2[3];
#pragma unroll
  for (int k = 0; k < 3; ++k) bc2[k] = bc2g[k];

  // ---- coarse samples: lane i owns z_i ----
  const float zi = nearv + (farv - nearv) * ((float)lane * (1.f / 63.f));
  float cx = fminf(fmaxf(fmaf(d0, zi, o0), -1.f), 1.f);
  float cy = fminf(fmaxf(fmaf(d1, zi, o1), -1.f), 1.f);
  float cz = fminf(fmaxf(fmaf(d2, zi, o2), -1.f), 1.f);
  float acc[16];
  density_mlp(dpk, bd2, cx, cy, cz, t, acc);
  const float sigma = expf(acc[0]);
  float geoc[15];
#pragma unroll
  for (int k = 0; k < 15; ++k) geoc[k] = acc[k + 1];

  // ---- coarse compositing -> pdf/cdf ----
  const float znext = __shfl_down(zi, 1, 64);
  const float cdelta = (lane < 63) ? (znext - zi) : sd;
  const float calpha = 1.f - expf(-cdelta * sigma);
  {
    float T = 1.f - calpha + 1e-15f;
    float Pincl = wave_scan_prod(T, lane);
    float Pexcl = __shfl_up(Pincl, 1, 64);
    if (lane == 0) Pexcl = 1.f;
    float wgt = calpha * Pexcl;

    float v = (lane >= 1 && lane <= 62) ? (wgt + 1e-5f) : 0.f;
    float tot = wave_reduce_sum(v);
    float S = wave_scan_sum(v, lane);
    float inv_tot = 1.f / tot;
    if (lane < 63) {
      s_cdf[w][lane] = S * inv_tot;  // lane 0 -> 0
      s_mid[w][lane] = 0.5f * (zi + znext);
    }
    s_cz[w][lane] = zi;
  }
  __syncthreads();

  // ---- inverse-CDF sampling (searchsorted right over cdf[0..62]) ----
  float nzv;
  {
    const float u = ((float)lane + 0.5f) * 0.015625f;
    int lo = 0, hi = 63;
    while (lo < hi) {
      int m = (lo + hi) >> 1;
      if (s_cdf[w][m] <= u) lo = m + 1; else hi = m;
    }
    int below = lo - 1;
    int above = (lo < 62) ? lo : 62;
    float c0 = s_cdf[w][below], c1 = s_cdf[w][above];
    float b0 = s_mid[w][below], b1 = s_mid[w][above];
    float dn = c1 - c0;
    dn = (dn < 1e-5f) ? 1.f : dn;
    float tt = (u - c0) / dn;
    nzv = fmaf(tt, (b1 - b0), b0);
  }

  // ---- fine density ----
  float fx = fminf(fmaxf(fmaf(d0, nzv, o0), -1.f), 1.f);
  float fy = fminf(fmaxf(fmaf(d1, nzv, o1), -1.f), 1.f);
  float fz = fminf(fmaxf(fmaf(d2, nzv, o2), -1.f), 1.f);
  density_mlp(dpk, bd2, fx, fy, fz, t, acc);
  const float nsigma = expf(acc[0]);
  float geof[15];
#pragma unroll
  for (int k = 0; k < 15; ++k) geof[k] = acc[k + 1];

  s_nz[w][lane] = nzv;
  __syncthreads();

  // ---- stable-merge ranks (both lists sorted) ----
  int r1, r2;
  {
    int lo = 0, hi = 64;
    while (lo < hi) { int m = (lo + hi) >> 1; if (s_nz[w][m] < zi) lo = m + 1; else hi = m; }
    r1 = lane + lo;  // coarse: count fine strictly less
  }
  {
    int lo = 0, hi = 64;
    while (lo < hi) { int m = (lo + hi) >> 1; if (s_cz[w][m] <= nzv) lo = m + 1; else hi = m; }
    r2 = lane + lo;  // fine: count coarse <= (stable: coarse first on ties)
  }
  s_zs[w][r1] = zi;  s_ss[w][r1] = sigma;
  s_zs[w][r2] = nzv; s_ss[w][r2] = nsigma;
  __syncthreads();

  // ---- composite over 128 sorted samples ----
  float w0, w1, wsum;
  {
    float z0 = s_zs[w][lane];
    float z0n = s_zs[w][lane + 1];
    float z1 = s_zs[w][lane + 64];
    float dl0 = z0n - z0;
    float dl1 = (lane < 63) ? (s_zs[w][lane + 65] - z1) : sd;
    float al0 = 1.f - expf(-dl0 * s_ss[w][lane]);
    float al1 = 1.f - expf(-dl1 * s_ss[w][lane + 64]);
    float T0 = 1.f - al0 + 1e-15f;
    float T1 = 1.f - al1 + 1e-15f;
    float P0 = wave_scan_prod(T0, lane);
    float P1 = wave_scan_prod(T1, lane);
    float prodLo = __shfl(P0, 63, 64);
    float e0 = __shfl_up(P0, 1, 64);
    float e1 = __shfl_up(P1, 1, 64);
    if (lane == 0) { e0 = 1.f; e1 = 1.f; }
    w0 = al0 * e0;
    w1 = al1 * prodLo * e1;
    wsum = wave_reduce_sum(w0 + w1);
    s_ws[w][lane] = w0;
    s_ws[w][lane + 64] = w1;
  }
  __syncthreads();

  // ---- color for owned samples (geo still in registers) ----
  const float wc = s_ws[w][r1];
  const float wf = s_ws[w][r2];
  float cr = 0.f, cg = 0.f, cb = 0.f;
  if (wc > 1e-4f) {
    float rgb[3];
    color_mlp(cpk, bc2, d0, d1, d2, geoc, rgb);
    cr = fmaf(wc, rgb[0], cr); cg = fmaf(wc, rgb[1], cg); cb = fmaf(wc, rgb[2], cb);
  }
  if (wf > 1e-4f) {
    float rgb[3];
    color_mlp(cpk, bc2, d0, d1, d2, geof, rgb);
    cr = fmaf(wf, rgb[0], cr); cg = fmaf(wf, rgb[1], cg); cb = fmaf(wf, rgb[2], cb);
  }
  cr = wave_reduce_sum(cr);
  cg = wave_reduce_sum(cg);
  cb = wave_reduce_sum(cb);

  if (lane == 0) {
    const float rem = 1.f - wsum;
    out[ray * 3 + 0] = cr + rem * bg[0];
    out[ray * 3 + 1] = cg + rem * bg[1];
    out[ray * 3 + 2] = cb + rem * bg[2];
  }
}

extern "C" void kernel_launch(void* const* d_in, const int* in_sizes, int n_in,
                              void* d_out, int out_size, void* d_ws, size_t ws_size,
                              hipStream_t stream) {
  const float* rays_o = (const float*)d_in[0];
  const float* rays_d = (const float*)d_in[1];
  const float* time_p = (const float*)d_in[2];
  const float* bg     = (const float*)d_in[3];
  const float* Wd1    = (const float*)d_in[4];
  const float* bd1    = (const float*)d_in[5];
  const float* Wd2    = (const float*)d_in[6];
  const float* bd2    = (const float*)d_in[7];
  const float* Wc1    = (const float*)d_in[8];
  const float* bc1    = (const float*)d_in[9];
  const float* Wc2    = (const float*)d_in[10];
  const float* bc2    = (const float*)d_in[11];

  float* pk = (float*)d_ws;  // 4096 floats = 16 KiB packed weights
  pack_weights<<<1, 64, 0, stream>>>(Wd1, bd1, Wd2, Wc1, bc1, Wc2, pk);
  nerf_render<<<NRAYS / 4, 256, 0, stream>>>(rays_o, rays_d, time_p, bg, bd2, bc2, pk,
                                             (float*)d_out);
}

// Round 2
// 76.917 us; speedup vs baseline: 1.2765x; 1.2765x over previous
//
#include <hip/hip_runtime.h>
#include <math.h>

#define NRAYS 8192

typedef __attribute__((ext_vector_type(8))) short bf16x8;
typedef __attribute__((ext_vector_type(4))) short bf16x4;
typedef __attribute__((ext_vector_type(2))) short bf16x2;
typedef __attribute__((ext_vector_type(4))) float f32x4;

__device__ __forceinline__ short f2bf(float f) {
  union { float f; unsigned u; } v; v.f = f;
  unsigned r = (v.u + 0x7FFFu + ((v.u >> 16) & 1u)) >> 16;
  return (short)r;
}
__device__ __forceinline__ float bf2f(short s) {
  union { unsigned u; float f; } v; v.u = ((unsigned)(unsigned short)s) << 16;
  return v.f;
}

// ---------------- wave-level primitives (wave64) ----------------
__device__ __forceinline__ float wave_scan_prod(float v, int lane) {
#pragma unroll
  for (int off = 1; off < 64; off <<= 1) {
    float n = __shfl_up(v, off, 64);
    if (lane >= off) v *= n;
  }
  return v;
}
__device__ __forceinline__ float wave_scan_sum(float v, int lane) {
#pragma unroll
  for (int off = 1; off < 64; off <<= 1) {
    float n = __shfl_up(v, off, 64);
    if (lane >= off) v += n;
  }
  return v;
}
__device__ __forceinline__ float wave_reduce_sum(float v) {
#pragma unroll
  for (int off = 32; off >= 1; off >>= 1) v += __shfl_xor(v, off, 64);
  return v;
}

// ---------------- weight fragment packing ----------------
// pk layout (shorts):
//   DA [4 mtiles][64 lanes][8]   @ 0     density GEMM1 A (Wd1 hi|hi-dup|lo + bd1 slot)
//   D2A[2 kt   ][64][8]          @ 2048  density GEMM2 A (Wd2^T)
//   CA [4 m    ][64][8]          @ 3072  color GEMM1 A (Wc1^T + bc1 at k=18)
//   C2A[2 kt   ][64][8]          @ 5120  color GEMM2 A (Wc2^T, rows 0..2)
__global__ void pack_weights(const float* __restrict__ Wd1, const float* __restrict__ bd1,
                             const float* __restrict__ Wd2, const float* __restrict__ Wc1,
                             const float* __restrict__ bc1, const float* __restrict__ Wc2,
                             short* __restrict__ pk) {
  const int l = threadIdx.x;
  const int g = l >> 4, c = l & 15;
  for (int m = 0; m < 4; ++m) {
    short e[8] = {0, 0, 0, 0, 0, 0, 0, 0};
    int nu = 16 * m + c;
    if (g == 0) {
      for (int i = 0; i < 4; ++i) { short h = f2bf(Wd1[i * 64 + nu]); e[i] = h; e[4 + i] = h; }
    } else if (g == 1) {
      for (int i = 0; i < 4; ++i) {
        short h = f2bf(Wd1[i * 64 + nu]);
        e[i] = f2bf(Wd1[i * 64 + nu] - bf2f(h));
      }
      e[4] = f2bf(bd1[nu]);
    }
    for (int i = 0; i < 8; ++i) pk[m * 512 + l * 8 + i] = e[i];
  }
  for (int kt = 0; kt < 2; ++kt)
    for (int i = 0; i < 8; ++i)
      pk[2048 + kt * 512 + l * 8 + i] = f2bf(Wd2[(32 * kt + 8 * g + i) * 16 + c]);
  for (int m = 0; m < 4; ++m) {
    int nu = 16 * m + c;
    for (int i = 0; i < 8; ++i) {
      int k = 8 * g + i;
      short e = 0;
      if (k < 18) e = f2bf(Wc1[k * 64 + nu]);
      else if (k == 18) e = f2bf(bc1[nu]);
      pk[3072 + m * 512 + l * 8 + i] = e;
    }
  }
  for (int kt = 0; kt < 2; ++kt)
    for (int i = 0; i < 8; ++i)
      pk[5120 + kt * 512 + l * 8 + i] =
          (c < 3) ? f2bf(Wc2[(32 * kt + 8 * g + i) * 3 + c]) : (short)0;
}

// ---------------- density pass via MFMA ----------------
// Returns raw sigma pre-exp (sraw) per owning lane; writes geo into Xc rows
// [xcBase .. xcBase+63].
__device__ __forceinline__ float density_pass(
    const short* __restrict__ pk, short* __restrict__ Hl, short* __restrict__ Xdl,
    short* __restrict__ Xcl, float* __restrict__ sigl, int lane, int g, int c,
    float x, float y, float z, short tHi, short tLo,
    float d0, float d1, float d2, const float* __restrict__ bd2g, int xcBase) {
  // 1. write per-sample augmented input (hi|lo split) to Xd
  {
    short xh = f2bf(x), yh = f2bf(y), zh = f2bf(z);
    bf16x8 p;
    p[0] = xh; p[1] = yh; p[2] = zh; p[3] = tHi;
    p[4] = f2bf(x - bf2f(xh)); p[5] = f2bf(y - bf2f(yh)); p[6] = f2bf(z - bf2f(zh)); p[7] = tLo;
    *(bf16x8*)&Xdl[lane * 8] = p;
  }
  __syncthreads();

  // 2. GEMM1: H^T[64 nu][64 s] = Wd1T_aug[64][32] * Xaug[32][64]
  bf16x8 A1[4];
#pragma unroll
  for (int m = 0; m < 4; ++m) A1[m] = *(const bf16x8*)(pk + m * 512 + lane * 8);
  f32x4 acc[4][4];
#pragma unroll
  for (int m = 0; m < 4; ++m)
#pragma unroll
    for (int n = 0; n < 4; ++n) acc[m][n] = (f32x4){0.f, 0.f, 0.f, 0.f};
#pragma unroll
  for (int n = 0; n < 4; ++n) {
    bf16x8 V = *(const bf16x8*)&Xdl[(16 * n + c) * 8];
    bf16x8 b = V;
    if (g == 1) { b[4] = (short)0x3F80; b[5] = 0; b[6] = 0; b[7] = 0; }
    if (g >= 2) {
#pragma unroll
      for (int i = 0; i < 8; ++i) b[i] = 0;
    }
#pragma unroll
    for (int m = 0; m < 4; ++m)
      acc[m][n] = __builtin_amdgcn_mfma_f32_16x16x32_bf16(A1[m], b, acc[m][n], 0, 0, 0);
  }
  // 3. relu + bf16 + store H[s][nu], stride 72 shorts (144B)
#pragma unroll
  for (int m = 0; m < 4; ++m)
#pragma unroll
    for (int n = 0; n < 4; ++n) {
      bf16x4 hv;
      hv[0] = f2bf(fmaxf(acc[m][n][0], 0.f));
      hv[1] = f2bf(fmaxf(acc[m][n][1], 0.f));
      hv[2] = f2bf(fmaxf(acc[m][n][2], 0.f));
      hv[3] = f2bf(fmaxf(acc[m][n][3], 0.f));
      *(bf16x4*)&Hl[(16 * n + c) * 72 + 16 * m + 4 * g] = hv;
    }
  __syncthreads();

  // 4. GEMM2: Out^T[16 o][64 s] = Wd2T[16][64] * H^T[64][64]
  bf16x8 A2[2];
  A2[0] = *(const bf16x8*)(pk + 2048 + lane * 8);
  A2[1] = *(const bf16x8*)(pk + 2048 + 512 + lane * 8);
  f32x4 o[4];
#pragma unroll
  for (int n = 0; n < 4; ++n) o[n] = (f32x4){0.f, 0.f, 0.f, 0.f};
#pragma unroll
  for (int n = 0; n < 4; ++n)
#pragma unroll
    for (int kt = 0; kt < 2; ++kt) {
      bf16x8 Bh = *(const bf16x8*)&Hl[(16 * n + c) * 72 + 32 * kt + 8 * g];
      o[n] = __builtin_amdgcn_mfma_f32_16x16x32_bf16(A2[kt], Bh, o[n], 0, 0, 0);
    }

  // 5. epilogue: +bd2; sigma scatter; geo -> Xc (48B rows)
  const float4 bd2v = *(const float4*)&bd2g[4 * g];
#pragma unroll
  for (int n = 0; n < 4; ++n) {
    o[n][0] += bd2v.x; o[n][1] += bd2v.y; o[n][2] += bd2v.z; o[n][3] += bd2v.w;
  }
  if (g == 0) {
#pragma unroll
    for (int n = 0; n < 4; ++n) sigl[16 * n + c] = o[n][0];
  }
#pragma unroll
  for (int n = 0; n < 4; ++n) {
    short* xr = &Xcl[(xcBase + 16 * n + c) * 24];
    bf16x2 p0, p1;
    p0[0] = (g == 0) ? f2bf(d2) : f2bf(o[n][0]);
    p0[1] = f2bf(o[n][1]);
    p1[0] = f2bf(o[n][2]);
    p1[1] = f2bf(o[n][3]);
    *(bf16x2*)&xr[2 + 4 * g] = p0;
    *(bf16x2*)&xr[4 + 4 * g] = p1;
    if (g == 0) { bf16x2 d01; d01[0] = f2bf(d0); d01[1] = f2bf(d1); *(bf16x2*)&xr[0] = d01; }
    if (g == 3) {
      bf16x2 one0; one0[0] = (short)0x3F80; one0[1] = 0;
      bf16x2 zz; zz[0] = 0; zz[1] = 0;
      *(bf16x2*)&xr[18] = one0; *(bf16x2*)&xr[20] = zz; *(bf16x2*)&xr[22] = zz;
    }
  }
  __syncthreads();
  return sigl[lane];
}

// ---------------- main renderer: one wave per ray, 2 rays per block --------
__global__ __launch_bounds__(128) void nerf_render(
    const float* __restrict__ rays_o, const float* __restrict__ rays_d,
    const float* __restrict__ time_p, const float* __restrict__ bg,
    const float* __restrict__ bd2g, const float* __restrict__ bc2g,
    const short* __restrict__ pk, float* __restrict__ out) {
  __shared__ __align__(16) short s_H[2][64 * 72];    // hidden acts, 144B rows
  __shared__ __align__(16) short s_Xc[2][128 * 24];  // color inputs, 48B rows
  __shared__ __align__(16) short s_Xd[2][64 * 8];    // density inputs, 16B rows
  __shared__ float s_cz[2][64], s_nz[2][64], s_cdf[2][64], s_mid[2][64];
  __shared__ float s_zs[2][128], s_ss[2][128], s_ws[2][128], s_wu[2][128];
  __shared__ float s_sig[2][64];

  const int lane = threadIdx.x & 63;
  const int g = lane >> 4, c = lane & 15;
  const int w = threadIdx.x >> 6;
  const int ray = (blockIdx.x << 1) + w;

  short* Hl = s_H[w];
  short* Xcl = s_Xc[w];
  short* Xdl = s_Xd[w];

  const float t = time_p[0];
  const short tHi = f2bf(t);
  const short tLo = f2bf(t - bf2f(tHi));
  const float o0 = rays_o[ray * 3 + 0], o1 = rays_o[ray * 3 + 1], o2 = rays_o[ray * 3 + 2];
  const float d0 = rays_d[ray * 3 + 0], d1 = rays_d[ray * 3 + 1], d2 = rays_d[ray * 3 + 2];

  // ---- near / far from aabb [-1,1]^3 ----
  float nearv, farv;
  {
    float i0 = 1.f / ((fabsf(d0) < 1e-9f) ? 1e-9f : d0);
    float i1 = 1.f / ((fabsf(d1) < 1e-9f) ? 1e-9f : d1);
    float i2 = 1.f / ((fabsf(d2) < 1e-9f) ? 1e-9f : d2);
    float a0 = (-1.f - o0) * i0, b0 = (1.f - o0) * i0;
    float a1 = (-1.f - o1) * i1, b1 = (1.f - o1) * i1;
    float a2 = (-1.f - o2) * i2, b2 = (1.f - o2) * i2;
    float tmin = fmaxf(fmaxf(fminf(a0, b0), fminf(a1, b1)), fminf(a2, b2));
    float tmax = fminf(fminf(fmaxf(a0, b0), fmaxf(a1, b1)), fmaxf(a2, b2));
    nearv = fmaxf(tmin, 0.05f);
    farv = (tmax < nearv) ? (nearv + 1e-2f) : tmax;
  }
  const float sd = (farv - nearv) * (1.f / 64.f);

  // ---- coarse samples ----
  const float zi = nearv + (farv - nearv) * ((float)lane * (1.f / 63.f));
  float cx = fminf(fmaxf(fmaf(d0, zi, o0), -1.f), 1.f);
  float cy = fminf(fmaxf(fmaf(d1, zi, o1), -1.f), 1.f);
  float cz = fminf(fmaxf(fmaf(d2, zi, o2), -1.f), 1.f);
  float sraw = density_pass(pk, Hl, Xdl, Xcl, s_sig[w], lane, g, c,
                            cx, cy, cz, tHi, tLo, d0, d1, d2, bd2g, 0);
  const float sigma = expf(sraw);

  // ---- coarse compositing -> pdf/cdf ----
  const float znext = __shfl_down(zi, 1, 64);
  const float cdelta = (lane < 63) ? (znext - zi) : sd;
  const float calpha = 1.f - expf(-cdelta * sigma);
  {
    float T = 1.f - calpha + 1e-15f;
    float Pincl = wave_scan_prod(T, lane);
    float Pexcl = __shfl_up(Pincl, 1, 64);
    if (lane == 0) Pexcl = 1.f;
    float wgt = calpha * Pexcl;

    float v = (lane >= 1 && lane <= 62) ? (wgt + 1e-5f) : 0.f;
    float tot = wave_reduce_sum(v);
    float S = wave_scan_sum(v, lane);
    float inv_tot = 1.f / tot;
    if (lane < 63) {
      s_cdf[w][lane] = S * inv_tot;
      s_mid[w][lane] = 0.5f * (zi + znext);
    }
    s_cz[w][lane] = zi;
  }
  __syncthreads();

  // ---- inverse-CDF sampling ----
  float nzv;
  {
    const float u = ((float)lane + 0.5f) * 0.015625f;
    int lo = 0, hi = 63;
    while (lo < hi) {
      int m = (lo + hi) >> 1;
      if (s_cdf[w][m] <= u) lo = m + 1; else hi = m;
    }
    int below = lo - 1;
    int above = (lo < 62) ? lo : 62;
    float c0 = s_cdf[w][below], c1 = s_cdf[w][above];
    float b0 = s_mid[w][below], b1 = s_mid[w][above];
    float dn = c1 - c0;
    dn = (dn < 1e-5f) ? 1.f : dn;
    float tt = (u - c0) / dn;
    nzv = fmaf(tt, (b1 - b0), b0);
  }

  // ---- fine density ----
  float fx = fminf(fmaxf(fmaf(d0, nzv, o0), -1.f), 1.f);
  float fy = fminf(fmaxf(fmaf(d1, nzv, o1), -1.f), 1.f);
  float fz = fminf(fmaxf(fmaf(d2, nzv, o2), -1.f), 1.f);
  float nsraw = density_pass(pk, Hl, Xdl, Xcl, s_sig[w], lane, g, c,
                             fx, fy, fz, tHi, tLo, d0, d1, d2, bd2g, 64);
  const float nsigma = expf(nsraw);

  s_nz[w][lane] = nzv;
  __syncthreads();

  // ---- stable-merge ranks ----
  int r1, r2;
  {
    int lo = 0, hi = 64;
    while (lo < hi) { int m = (lo + hi) >> 1; if (s_nz[w][m] < zi) lo = m + 1; else hi = m; }
    r1 = lane + lo;
  }
  {
    int lo = 0, hi = 64;
    while (lo < hi) { int m = (lo + hi) >> 1; if (s_cz[w][m] <= nzv) lo = m + 1; else hi = m; }
    r2 = lane + lo;
  }
  s_zs[w][r1] = zi;  s_ss[w][r1] = sigma;
  s_zs[w][r2] = nzv; s_ss[w][r2] = nsigma;
  __syncthreads();

  // ---- composite over 128 sorted samples ----
  float w0, w1, wsum;
  {
    float z0 = s_zs[w][lane];
    float z0n = s_zs[w][lane + 1];
    float z1 = s_zs[w][lane + 64];
    float dl0 = z0n - z0;
    float dl1 = (lane < 63) ? (s_zs[w][lane + 65] - z1) : sd;
    float al0 = 1.f - expf(-dl0 * s_ss[w][lane]);
    float al1 = 1.f - expf(-dl1 * s_ss[w][lane + 64]);
    float T0 = 1.f - al0 + 1e-15f;
    float T1 = 1.f - al1 + 1e-15f;
    float P0 = wave_scan_prod(T0, lane);
    float P1 = wave_scan_prod(T1, lane);
    float prodLo = __shfl(P0, 63, 64);
    float e0 = __shfl_up(P0, 1, 64);
    float e1 = __shfl_up(P1, 1, 64);
    if (lane == 0) { e0 = 1.f; e1 = 1.f; }
    w0 = al0 * e0;
    w1 = al1 * prodLo * e1;
    wsum = wave_reduce_sum(w0 + w1);
    s_ws[w][lane] = w0;
    s_ws[w][lane + 64] = w1;
  }
  __syncthreads();

  // ---- per-sample weights back in unmerged order ----
  const float wc = s_ws[w][r1];
  const float wf = s_ws[w][r2];
  s_wu[w][lane] = wc;
  s_wu[w][64 + lane] = wf;
  const unsigned long long mC = __ballot(wc > 1e-4f);
  const unsigned long long mF = __ballot(wf > 1e-4f);
  __syncthreads();

  // ---- color MLP via MFMA, two 64-sample halves, per-16 tile skip ----
  bf16x8 CA[4];
#pragma unroll
  for (int m = 0; m < 4; ++m) CA[m] = *(const bf16x8*)(pk + 3072 + m * 512 + lane * 8);
  bf16x8 C2A[2];
  C2A[0] = *(const bf16x8*)(pk + 5120 + lane * 8);
  C2A[1] = *(const bf16x8*)(pk + 5120 + 512 + lane * 8);
  const float bc20 = bc2g[0], bc21 = bc2g[1], bc22 = bc2g[2];

  float cr = 0.f, cgr = 0.f, cb = 0.f;
  const int xoff = (g < 2) ? 8 * g : 16;
#pragma unroll
  for (int half = 0; half < 2; ++half) {
    const unsigned long long mm = half ? mF : mC;
    // GEMM1 + relu + store H per live tile
#pragma unroll
    for (int n = 0; n < 4; ++n) {
      if ((mm >> (16 * n)) & 0xFFFFull) {
        bf16x8 V = *(const bf16x8*)&Xcl[(64 * half + 16 * n + c) * 24 + xoff];
        if (g == 3) {
#pragma unroll
          for (int i = 0; i < 8; ++i) V[i] = 0;
        }
#pragma unroll
        for (int m = 0; m < 4; ++m) {
          f32x4 a = (f32x4){0.f, 0.f, 0.f, 0.f};
          a = __builtin_amdgcn_mfma_f32_16x16x32_bf16(CA[m], V, a, 0, 0, 0);
          bf16x4 hv;
          hv[0] = f2bf(fmaxf(a[0], 0.f));
          hv[1] = f2bf(fmaxf(a[1], 0.f));
          hv[2] = f2bf(fmaxf(a[2], 0.f));
          hv[3] = f2bf(fmaxf(a[3], 0.f));
          *(bf16x4*)&Hl[(16 * n + c) * 72 + 16 * m + 4 * g] = hv;
        }
      }
    }
    __syncthreads();
    // GEMM2 + sigmoid + weighted accumulate per live tile
#pragma unroll
    for (int n = 0; n < 4; ++n) {
      if ((mm >> (16 * n)) & 0xFFFFull) {
        f32x4 o = (f32x4){0.f, 0.f, 0.f, 0.f};
#pragma unroll
        for (int kt = 0; kt < 2; ++kt) {
          bf16x8 Bh = *(const bf16x8*)&Hl[(16 * n + c) * 72 + 32 * kt + 8 * g];
          o = __builtin_amdgcn_mfma_f32_16x16x32_bf16(C2A[kt], Bh, o, 0, 0, 0);
        }
        if (g == 0) {
          float wgt = s_wu[w][64 * half + 16 * n + c];
          if (wgt > 1e-4f) {
            cr  += wgt / (1.f + expf(-(o[0] + bc20)));
            cgr += wgt / (1.f + expf(-(o[1] + bc21)));
            cb  += wgt / (1.f + expf(-(o[2] + bc22)));
          }
        }
      }
    }
    __syncthreads();
  }

  cr = wave_reduce_sum(cr);
  cgr = wave_reduce_sum(cgr);
  cb = wave_reduce_sum(cb);

  if (lane == 0) {
    const float rem = 1.f - wsum;
    out[ray * 3 + 0] = cr + rem * bg[0];
    out[ray * 3 + 1] = cgr + rem * bg[1];
    out[ray * 3 + 2] = cb + rem * bg[2];
  }
}

extern "C" void kernel_launch(void* const* d_in, const int* in_sizes, int n_in,
                              void* d_out, int out_size, void* d_ws, size_t ws_size,
                              hipStream_t stream) {
  const float* rays_o = (const float*)d_in[0];
  const float* rays_d = (const float*)d_in[1];
  const float* time_p = (const float*)d_in[2];
  const float* bg     = (const float*)d_in[3];
  const float* Wd1    = (const float*)d_in[4];
  const float* bd1    = (const float*)d_in[5];
  const float* Wd2    = (const float*)d_in[6];
  const float* bd2    = (const float*)d_in[7];
  const float* Wc1    = (const float*)d_in[8];
  const float* bc1    = (const float*)d_in[9];
  const float* Wc2    = (const float*)d_in[10];
  const float* bc2    = (const float*)d_in[11];

  short* pk = (short*)d_ws;  // 12 KiB packed weight fragments
  pack_weights<<<1, 64, 0, stream>>>(Wd1, bd1, Wd2, Wc1, bc1, Wc2, pk);
  nerf_render<<<NRAYS / 2, 128, 0, stream>>>(rays_o, rays_d, time_p, bg, bd2, bc2, pk,
                                             (float*)d_out);
}

// Round 3
// 55.119 us; speedup vs baseline: 1.7813x; 1.3955x over previous
//
#include <hip/hip_runtime.h>
#include <math.h>

#define NRAYS 8192

typedef __attribute__((ext_vector_type(8))) short bf16x8;
typedef __attribute__((ext_vector_type(4))) float f32x4;
typedef __attribute__((ext_vector_type(2))) unsigned u32x2;
typedef __attribute__((ext_vector_type(4))) unsigned u32x4;

#define FENCE asm volatile("" ::: "memory")

__device__ __forceinline__ short f2bf(float f) {
  union { float f; unsigned u; } v; v.f = f;
  unsigned r = (v.u + 0x7FFFu + ((v.u >> 16) & 1u)) >> 16;
  return (short)r;
}
__device__ __forceinline__ float bf2f(short s) {
  union { unsigned u; float f; } v; v.u = ((unsigned)(unsigned short)s) << 16;
  return v.f;
}
// HW packed f32->bf16 (RNE): dst = {lo=bf16(a), hi=bf16(b)}
__device__ __forceinline__ unsigned cvt2(float a, float b) {
  unsigned r;
  asm("v_cvt_pk_bf16_f32 %0, %1, %2" : "=v"(r) : "v"(a), "v"(b));
  return r;
}
__device__ __forceinline__ float fast_rcp(float x) {
  float r;
  asm("v_rcp_f32 %0, %1" : "=v"(r) : "v"(x));
  return r;
}
__device__ __forceinline__ void store_relu4(short* p, f32x4 a) {  // p 8B-aligned
  u32x2 v;
  v[0] = cvt2(fmaxf(a[0], 0.f), fmaxf(a[1], 0.f));
  v[1] = cvt2(fmaxf(a[2], 0.f), fmaxf(a[3], 0.f));
  *(u32x2*)p = v;
}
// coarse z formula — MUST be the single definition used everywhere (bit-exact reuse)
__device__ __forceinline__ float zcoarse(float nearv, float span, int m) {
  return fmaf(span, (float)m * (1.f / 63.f), nearv);
}

// ---------------- wave-level primitives (wave64) ----------------
__device__ __forceinline__ float wave_scan_prod(float v, int lane) {
#pragma unroll
  for (int off = 1; off < 64; off <<= 1) {
    float n = __shfl_up(v, off, 64);
    if (lane >= off) v *= n;
  }
  return v;
}
__device__ __forceinline__ float wave_scan_sum(float v, int lane) {
#pragma unroll
  for (int off = 1; off < 64; off <<= 1) {
    float n = __shfl_up(v, off, 64);
    if (lane >= off) v += n;
  }
  return v;
}
__device__ __forceinline__ float wave_reduce_sum(float v) {
#pragma unroll
  for (int off = 32; off >= 1; off >>= 1) v += __shfl_xor(v, off, 64);
  return v;
}

// ---------------- weight fragment packing (unchanged layout) ----------------
__global__ void pack_weights(const float* __restrict__ Wd1, const float* __restrict__ bd1,
                             const float* __restrict__ Wd2, const float* __restrict__ Wc1,
                             const float* __restrict__ bc1, const float* __restrict__ Wc2,
                             short* __restrict__ pk) {
  const int l = threadIdx.x;
  const int g = l >> 4, c = l & 15;
  for (int m = 0; m < 4; ++m) {
    short e[8] = {0, 0, 0, 0, 0, 0, 0, 0};
    int nu = 16 * m + c;
    if (g == 0) {
      for (int i = 0; i < 4; ++i) { short h = f2bf(Wd1[i * 64 + nu]); e[i] = h; e[4 + i] = h; }
    } else if (g == 1) {
      for (int i = 0; i < 4; ++i) {
        short h = f2bf(Wd1[i * 64 + nu]);
        e[i] = f2bf(Wd1[i * 64 + nu] - bf2f(h));
      }
      e[4] = f2bf(bd1[nu]);
    }
    for (int i = 0; i < 8; ++i) pk[m * 512 + l * 8 + i] = e[i];
  }
  for (int kt = 0; kt < 2; ++kt)
    for (int i = 0; i < 8; ++i)
      pk[2048 + kt * 512 + l * 8 + i] = f2bf(Wd2[(32 * kt + 8 * g + i) * 16 + c]);
  for (int m = 0; m < 4; ++m) {
    int nu = 16 * m + c;
    for (int i = 0; i < 8; ++i) {
      int k = 8 * g + i;
      short e = 0;
      if (k < 18) e = f2bf(Wc1[k * 64 + nu]);
      else if (k == 18) e = f2bf(bc1[nu]);
      pk[3072 + m * 512 + l * 8 + i] = e;
    }
  }
  for (int kt = 0; kt < 2; ++kt)
    for (int i = 0; i < 8; ++i)
      pk[5120 + kt * 512 + l * 8 + i] =
          (c < 3) ? f2bf(Wc2[(32 * kt + 8 * g + i) * 3 + c]) : (short)0;
}

// ---------------- density pass via MFMA (intra-wave, no barriers) ----------
__device__ __forceinline__ float density_pass(
    const short* __restrict__ pk, short* __restrict__ Hl, short* __restrict__ Xdl,
    short* __restrict__ Xcl, int lane, int g, int c,
    float x, float y, float z, float tf, float tLoF,
    float d0, float d1, float d2, const float* __restrict__ bd2g, int xcBase) {
  // 1. pack per-sample augmented input (hi|lo split) to Xd via cvt_pk
  {
    unsigned w0 = cvt2(x, y);
    unsigned w1 = cvt2(z, tf);
    union { unsigned u; float f; } ux, uy, uz;
    ux.u = w0 << 16; uy.u = w0 & 0xFFFF0000u; uz.u = w1 << 16;
    unsigned w2 = cvt2(x - ux.f, y - uy.f);
    unsigned w3 = cvt2(z - uz.f, tLoF);
    u32x4 pv; pv[0] = w0; pv[1] = w1; pv[2] = w2; pv[3] = w3;
    *(u32x4*)&Xdl[lane * 8] = pv;
  }
  FENCE;

  // 2. GEMM1: H^T[64 nu][64 s]
  bf16x8 A1[4];
#pragma unroll
  for (int m = 0; m < 4; ++m) A1[m] = *(const bf16x8*)(pk + m * 512 + lane * 8);
  f32x4 acc[4][4];
#pragma unroll
  for (int m = 0; m < 4; ++m)
#pragma unroll
    for (int n = 0; n < 4; ++n) acc[m][n] = (f32x4){0.f, 0.f, 0.f, 0.f};
#pragma unroll
  for (int n = 0; n < 4; ++n) {
    bf16x8 b = *(const bf16x8*)&Xdl[(16 * n + c) * 8];
    if (g == 1) b[4] = (short)0x3F80;  // bias slot k=12 -> 1.0 (A zero for k>12 in g1, all k in g>=2)
#pragma unroll
    for (int m = 0; m < 4; ++m)
      acc[m][n] = __builtin_amdgcn_mfma_f32_16x16x32_bf16(A1[m], b, acc[m][n], 0, 0, 0);
  }
  FENCE;
  // 3. relu + packed cvt + store H[s][nu], stride 72 shorts
#pragma unroll
  for (int m = 0; m < 4; ++m)
#pragma unroll
    for (int n = 0; n < 4; ++n)
      store_relu4(&Hl[(16 * n + c) * 72 + 16 * m + 4 * g], acc[m][n]);
  FENCE;

  // 4. GEMM2: Out^T[16 o][64 s]
  bf16x8 A2[2];
  A2[0] = *(const bf16x8*)(pk + 2048 + lane * 8);
  A2[1] = *(const bf16x8*)(pk + 2048 + 512 + lane * 8);
  f32x4 o[4];
#pragma unroll
  for (int n = 0; n < 4; ++n) o[n] = (f32x4){0.f, 0.f, 0.f, 0.f};
#pragma unroll
  for (int n = 0; n < 4; ++n)
#pragma unroll
    for (int kt = 0; kt < 2; ++kt) {
      bf16x8 Bh = *(const bf16x8*)&Hl[(16 * n + c) * 72 + 32 * kt + 8 * g];
      o[n] = __builtin_amdgcn_mfma_f32_16x16x32_bf16(A2[kt], Bh, o[n], 0, 0, 0);
    }
  FENCE;

  // 5. epilogue: +bd2; geo -> Xc; sigma via shuffle (no LDS round-trip)
  const float4 bd2v = *(const float4*)&bd2g[4 * g];
#pragma unroll
  for (int n = 0; n < 4; ++n) {
    o[n][0] += bd2v.x; o[n][1] += bd2v.y; o[n][2] += bd2v.z; o[n][3] += bd2v.w;
  }
#pragma unroll
  for (int n = 0; n < 4; ++n) {
    short* xr = &Xcl[(xcBase + 16 * n + c) * 24];
    unsigned lo = cvt2((g == 0) ? d2 : o[n][0], o[n][1]);
    unsigned hi = cvt2(o[n][2], o[n][3]);
    ((unsigned*)xr)[0 + 0] = ((unsigned*)0, 0), 0;  // placeholder removed below
  }
  // (rewritten without placeholder)
#pragma unroll
  for (int n = 0; n < 4; ++n) {
    short* xr = &Xcl[(xcBase + 16 * n + c) * 24];
    unsigned lo = cvt2((g == 0) ? d2 : o[n][0], o[n][1]);
    unsigned hi = cvt2(o[n][2], o[n][3]);
    *(unsigned*)(xr + 2 + 4 * g) = lo;   // 4B-aligned
    *(unsigned*)(xr + 4 + 4 * g) = hi;
    if (g == 0) *(unsigned*)xr = cvt2(d0, d1);
    if (g == 3) {
      *(unsigned*)(xr + 18) = 0x00003F80u;  // col18=1.0, col19=0
      u32x2 zz; zz[0] = 0; zz[1] = 0;
      *(u32x2*)(xr + 20) = zz;              // cols 20..23 = 0 (8B-aligned)
    }
  }
  FENCE;
  float t0 = __shfl(o[0][0], c);
  float t1 = __shfl(o[1][0], c);
  float t2 = __shfl(o[2][0], c);
  float t3 = __shfl(o[3][0], c);
  return (g == 0) ? t0 : (g == 1) ? t1 : (g == 2) ? t2 : t3;
}

// ---------------- main renderer: one ray = one wave = one block ------------
__global__ __launch_bounds__(64, 3) void nerf_render(
    const float* __restrict__ rays_o, const float* __restrict__ rays_d,
    const float* __restrict__ time_p, const float* __restrict__ bg,
    const float* __restrict__ bd2g, const float* __restrict__ bc2g,
    const short* __restrict__ pk, float* __restrict__ out) {
  // 16384B shared, lifetime-aliased:
  //  [0..9215]      H (64 rows x 144B)  | also Xd[1KB] during GEMM1 | also zs/ss[1KB] during composite
  //  [9216..15359]  Xc (128 rows x 48B)
  //  [15360..15871] nz[64]+cdf[64]      | also wu[128] during color
  //  [15872..16383] ws[128]
  __shared__ __align__(16) char smem[16384];
  short* Hl  = (short*)smem;
  short* Xdl = (short*)smem;
  float* zsl = (float*)smem;
  float* ssl = (float*)(smem + 512);
  short* Xcl = (short*)(smem + 9216);
  float* nzl = (float*)(smem + 15360);
  float* cdfl = (float*)(smem + 15616);
  float* wul = (float*)(smem + 15360);
  float* wsl = (float*)(smem + 15872);

  const int lane = threadIdx.x;
  const int g = lane >> 4, c = lane & 15;
  const int ray = blockIdx.x;

  const float tf = time_p[0];
  union { unsigned u; float f; } th; th.u = cvt2(tf, tf) << 16;
  const float tLoF = tf - th.f;
  const float o0 = rays_o[ray * 3 + 0], o1 = rays_o[ray * 3 + 1], o2 = rays_o[ray * 3 + 2];
  const float d0 = rays_d[ray * 3 + 0], d1 = rays_d[ray * 3 + 1], d2 = rays_d[ray * 3 + 2];

  // ---- near / far from aabb [-1,1]^3 ----
  float nearv, farv;
  {
    float i0 = fast_rcp((fabsf(d0) < 1e-9f) ? 1e-9f : d0);
    float i1 = fast_rcp((fabsf(d1) < 1e-9f) ? 1e-9f : d1);
    float i2 = fast_rcp((fabsf(d2) < 1e-9f) ? 1e-9f : d2);
    float a0 = (-1.f - o0) * i0, b0 = (1.f - o0) * i0;
    float a1 = (-1.f - o1) * i1, b1 = (1.f - o1) * i1;
    float a2 = (-1.f - o2) * i2, b2 = (1.f - o2) * i2;
    float tmin = fmaxf(fmaxf(fminf(a0, b0), fminf(a1, b1)), fminf(a2, b2));
    float tmax = fminf(fminf(fmaxf(a0, b0), fmaxf(a1, b1)), fmaxf(a2, b2));
    nearv = fmaxf(tmin, 0.05f);
    farv = (tmax < nearv) ? (nearv + 1e-2f) : tmax;
  }
  const float span = farv - nearv;
  const float sd = span * (1.f / 64.f);

  // ---- coarse pass ----
  const float zi = zcoarse(nearv, span, lane);
  float cx = fminf(fmaxf(fmaf(d0, zi, o0), -1.f), 1.f);
  float cy = fminf(fmaxf(fmaf(d1, zi, o1), -1.f), 1.f);
  float cz = fminf(fmaxf(fmaf(d2, zi, o2), -1.f), 1.f);
  float sraw = density_pass(pk, Hl, Xdl, Xcl, lane, g, c,
                            cx, cy, cz, tf, tLoF, d0, d1, d2, bd2g, 0);
  const float sigma = __expf(sraw);

  // ---- coarse compositing -> cdf ----
  const float znext = __shfl_down(zi, 1, 64);
  const float cdelta = (lane < 63) ? (znext - zi) : sd;
  const float calpha = 1.f - __expf(-cdelta * sigma);
  {
    float T = 1.f - calpha + 1e-15f;
    float Pincl = wave_scan_prod(T, lane);
    float Pexcl = __shfl_up(Pincl, 1, 64);
    if (lane == 0) Pexcl = 1.f;
    float wgt = calpha * Pexcl;
    float v = (lane >= 1 && lane <= 62) ? (wgt + 1e-5f) : 0.f;
    float tot = wave_reduce_sum(v);
    float S = wave_scan_sum(v, lane);
    float inv_tot = fast_rcp(tot);
    if (lane < 63) cdfl[lane] = S * inv_tot;
  }
  FENCE;

  // ---- inverse-CDF resampling (bins computed analytically) ----
  float nzv;
  {
    const float u = ((float)lane + 0.5f) * 0.015625f;
    int lo = 0, hi = 63;
    while (lo < hi) {
      int m = (lo + hi) >> 1;
      if (cdfl[m] <= u) lo = m + 1; else hi = m;
    }
    int below = lo - 1;
    int above = (lo < 62) ? lo : 62;
    float c0 = cdfl[below], c1 = cdfl[above];
    float b0 = 0.5f * (zcoarse(nearv, span, below) + zcoarse(nearv, span, below + 1));
    float b1 = 0.5f * (zcoarse(nearv, span, above) + zcoarse(nearv, span, above + 1));
    float dn = c1 - c0;
    dn = (dn < 1e-5f) ? 1.f : dn;
    nzv = fmaf((u - c0) * fast_rcp(dn), (b1 - b0), b0);
  }
  nzl[lane] = nzv;
  FENCE;

  // ---- fine pass ----
  float fx = fminf(fmaxf(fmaf(d0, nzv, o0), -1.f), 1.f);
  float fy = fminf(fmaxf(fmaf(d1, nzv, o1), -1.f), 1.f);
  float fz = fminf(fmaxf(fmaf(d2, nzv, o2), -1.f), 1.f);
  float nsraw = density_pass(pk, Hl, Xdl, Xcl, lane, g, c,
                             fx, fy, fz, tf, tLoF, d0, d1, d2, bd2g, 64);
  const float nsigma = __expf(nsraw);
  FENCE;

  // ---- stable-merge ranks: coarse analytic, fine via LDS ----
  int r1, r2;
  {
    int lo = 0, hi = 64;
    while (lo < hi) { int m = (lo + hi) >> 1; if (nzl[m] < zi) lo = m + 1; else hi = m; }
    r1 = lane + lo;
  }
  {
    int lo = 0, hi = 64;
    while (lo < hi) {
      int m = (lo + hi) >> 1;
      if (zcoarse(nearv, span, m) <= nzv) lo = m + 1; else hi = m;
    }
    r2 = lane + lo;
  }
  FENCE;
  zsl[r1] = zi;  ssl[r1] = sigma;
  zsl[r2] = nzv; ssl[r2] = nsigma;
  FENCE;

  // ---- composite over 128 sorted samples ----
  float w0, w1, wsum;
  {
    float z0 = zsl[lane];
    float z0n = zsl[lane + 1];
    float z1 = zsl[lane + 64];
    float dl0 = z0n - z0;
    float dl1 = (lane < 63) ? (zsl[lane + 65] - z1) : sd;
    float al0 = 1.f - __expf(-dl0 * ssl[lane]);
    float al1 = 1.f - __expf(-dl1 * ssl[lane + 64]);
    float T0 = 1.f - al0 + 1e-15f;
    float T1 = 1.f - al1 + 1e-15f;
    float P0 = wave_scan_prod(T0, lane);
    float P1 = wave_scan_prod(T1, lane);
    float prodLo = __shfl(P0, 63, 64);
    float e0 = __shfl_up(P0, 1, 64);
    float e1 = __shfl_up(P1, 1, 64);
    if (lane == 0) { e0 = 1.f; e1 = 1.f; }
    w0 = al0 * e0;
    w1 = al1 * prodLo * e1;
    wsum = wave_reduce_sum(w0 + w1);
    wsl[lane] = w0;
    wsl[lane + 64] = w1;
  }
  FENCE;

  // ---- weights back in unmerged order ----
  const float wc = wsl[r1];
  const float wf = wsl[r2];
  FENCE;
  wul[lane] = wc;
  wul[64 + lane] = wf;
  const unsigned long long mC = __ballot(wc > 1e-4f);
  const unsigned long long mF = __ballot(wf > 1e-4f);
  FENCE;

  // ---- color MLP via MFMA, per-16-sample tile skip ----
  bf16x8 CA[4];
#pragma unroll
  for (int m = 0; m < 4; ++m) CA[m] = *(const bf16x8*)(pk + 3072 + m * 512 + lane * 8);
  bf16x8 C2A[2];
  C2A[0] = *(const bf16x8*)(pk + 5120 + lane * 8);
  C2A[1] = *(const bf16x8*)(pk + 5120 + 512 + lane * 8);
  const float bc20 = bc2g[0], bc21 = bc2g[1], bc22 = bc2g[2];

  float cr = 0.f, cgr = 0.f, cb = 0.f;
  const int xoff = (g < 2) ? 8 * g : 16;
#pragma unroll
  for (int half = 0; half < 2; ++half) {
    const unsigned long long mm = half ? mF : mC;
#pragma unroll
    for (int n = 0; n < 4; ++n) {
      if ((mm >> (16 * n)) & 0xFFFFull) {
        bf16x8 V = *(const bf16x8*)&Xcl[(64 * half + 16 * n + c) * 24 + xoff];
#pragma unroll
        for (int m = 0; m < 4; ++m) {
          f32x4 a = (f32x4){0.f, 0.f, 0.f, 0.f};
          a = __builtin_amdgcn_mfma_f32_16x16x32_bf16(CA[m], V, a, 0, 0, 0);
          store_relu4(&Hl[(16 * n + c) * 72 + 16 * m + 4 * g], a);
        }
      }
    }
    FENCE;
#pragma unroll
    for (int n = 0; n < 4; ++n) {
      if ((mm >> (16 * n)) & 0xFFFFull) {
        f32x4 o = (f32x4){0.f, 0.f, 0.f, 0.f};
#pragma unroll
        for (int kt = 0; kt < 2; ++kt) {
          bf16x8 Bh = *(const bf16x8*)&Hl[(16 * n + c) * 72 + 32 * kt + 8 * g];
          o = __builtin_amdgcn_mfma_f32_16x16x32_bf16(C2A[kt], Bh, o, 0, 0, 0);
        }
        if (g == 0) {
          float wgt = wul[64 * half + 16 * n + c];
          if (wgt > 1e-4f) {
            cr  += wgt * fast_rcp(1.f + __expf(-(o[0] + bc20)));
            cgr += wgt * fast_rcp(1.f + __expf(-(o[1] + bc21)));
            cb  += wgt * fast_rcp(1.f + __expf(-(o[2] + bc22)));
          }
        }
      }
    }
    FENCE;
  }

  cr = wave_reduce_sum(cr);
  cgr = wave_reduce_sum(cgr);
  cb = wave_reduce_sum(cb);

  if (lane == 0) {
    const float rem = 1.f - wsum;
    out[ray * 3 + 0] = cr + rem * bg[0];
    out[ray * 3 + 1] = cgr + rem * bg[1];
    out[ray * 3 + 2] = cb + rem * bg[2];
  }
}

extern "C" void kernel_launch(void* const* d_in, const int* in_sizes, int n_in,
                              void* d_out, int out_size, void* d_ws, size_t ws_size,
                              hipStream_t stream) {
  const float* rays_o = (const float*)d_in[0];
  const float* rays_d = (const float*)d_in[1];
  const float* time_p = (const float*)d_in[2];
  const float* bg     = (const float*)d_in[3];
  const float* Wd1    = (const float*)d_in[4];
  const float* bd1    = (const float*)d_in[5];
  const float* Wd2    = (const float*)d_in[6];
  const float* bd2    = (const float*)d_in[7];
  const float* Wc1    = (const float*)d_in[8];
  const float* bc1    = (const float*)d_in[9];
  const float* Wc2    = (const float*)d_in[10];
  const float* bc2    = (const float*)d_in[11];

  short* pk = (short*)d_ws;  // 12 KiB packed weight fragments
  pack_weights<<<1, 64, 0, stream>>>(Wd1, bd1, Wd2, Wc1, bc1, Wc2, pk);
  nerf_render<<<NRAYS, 64, 0, stream>>>(rays_o, rays_d, time_p, bg, bd2, bc2, pk,
                                        (float*)d_out);
}

// Round 5
// 44.296 us; speedup vs baseline: 2.2165x; 1.2443x over previous
//
#include <hip/hip_runtime.h>
#include <math.h>

#define NRAYS 8192

typedef __attribute__((ext_vector_type(8))) short bf16x8;
typedef __attribute__((ext_vector_type(4))) float f32x4;
typedef __attribute__((ext_vector_type(4))) unsigned u32x4;

#define FENCE asm volatile("" ::: "memory")

__device__ __forceinline__ short f2bf(float f) {
  union { float f; unsigned u; } v; v.f = f;
  unsigned r = (v.u + 0x7FFFu + ((v.u >> 16) & 1u)) >> 16;
  return (short)r;
}
__device__ __forceinline__ float bf2f(short s) {
  union { unsigned u; float f; } v; v.u = ((unsigned)(unsigned short)s) << 16;
  return v.f;
}
// HW packed f32->bf16 (RNE): dst = {lo=bf16(a), hi=bf16(b)}
__device__ __forceinline__ unsigned cvt2(float a, float b) {
  unsigned r;
  asm("v_cvt_pk_bf16_f32 %0, %1, %2" : "=v"(r) : "v"(a), "v"(b));
  return r;
}
__device__ __forceinline__ unsigned cvtr(float a, float b) {  // relu + pack
  return cvt2(fmaxf(a, 0.f), fmaxf(b, 0.f));
}
__device__ __forceinline__ short bf1(float a) { return (short)cvt2(a, a); }
__device__ __forceinline__ float fast_rcp(float x) {
  float r;
  asm("v_rcp_f32 %0, %1" : "=v"(r) : "v"(x));
  return r;
}
__device__ __forceinline__ bf16x8 pack_b(unsigned a, unsigned b, unsigned c, unsigned d) {
  union { u32x4 u; bf16x8 v; } x;
  x.u = (u32x4){a, b, c, d};
  return x.v;
}
// coarse z formula — single definition (bit-exact reuse everywhere)
__device__ __forceinline__ float zcoarse(float nearv, float span, int m) {
  return fmaf(span, (float)m * (1.f / 63.f), nearv);
}

// ---------------- wave-level primitives (wave64) ----------------
__device__ __forceinline__ float wave_scan_prod(float v, int lane) {
#pragma unroll
  for (int off = 1; off < 64; off <<= 1) {
    float n = __shfl_up(v, off, 64);
    if (lane >= off) v *= n;
  }
  return v;
}
__device__ __forceinline__ float wave_scan_sum(float v, int lane) {
#pragma unroll
  for (int off = 1; off < 64; off <<= 1) {
    float n = __shfl_up(v, off, 64);
    if (lane >= off) v += n;
  }
  return v;
}
__device__ __forceinline__ float wave_reduce_sum(float v) {
#pragma unroll
  for (int off = 32; off >= 1; off >>= 1) v += __shfl_xor(v, off, 64);
  return v;
}

// ---------------- weight fragment packing (64 threads, round-3 math) --------
// pk (shorts): A1 @0 [4m][64][8] | A2 @2048 [2kt][64][8] | CA @3072 [4m][64][8]
//              C2A @5120 [2kt][64][8]
// GEMM2 A-frags use k-permutation: elem (kt,g,i) <-> nu = 32kt+16(i>>2)+4g+(i&3)
__global__ void pack_weights(const float* __restrict__ Wd1, const float* __restrict__ bd1,
                             const float* __restrict__ Wd2, const float* __restrict__ Wc1,
                             const float* __restrict__ bc1, const float* __restrict__ Wc2,
                             short* __restrict__ pk) {
  const int l = threadIdx.x;  // 64 threads
  const int g = l >> 4, c = l & 15;
  // density GEMM1 A: xvec = [xh,yh,zh,th | xlo,ylo,zlo,tlo], g1 slot4 = bias (B=1.0)
  for (int m = 0; m < 4; ++m) {
    int nu = 16 * m + c;
    short e[8] = {0, 0, 0, 0, 0, 0, 0, 0};
    if (g == 0) {
      for (int i = 0; i < 4; ++i) {
        short h = f2bf(Wd1[i * 64 + nu]);
        e[i] = h;
        e[4 + i] = h;
      }
    } else if (g == 1) {
      for (int i = 0; i < 4; ++i) {
        float w = Wd1[i * 64 + nu];
        e[i] = f2bf(w - bf2f(f2bf(w)));
      }
      e[4] = f2bf(bd1[nu]);
    }
    for (int i = 0; i < 8; ++i) pk[m * 512 + l * 8 + i] = e[i];
  }
  // density GEMM2 A (k-permuted)
  for (int kt = 0; kt < 2; ++kt)
    for (int i = 0; i < 8; ++i) {
      int nu = 32 * kt + 16 * (i >> 2) + 4 * g + (i & 3);
      pk[2048 + kt * 512 + l * 8 + i] = f2bf(Wd2[nu * 16 + c]);
    }
  // color GEMM1 A: k0-14=geo (Wc1 rows 3..17), k15=bc1, k16-18=dir (rows 0..2)
  for (int m = 0; m < 4; ++m) {
    int nu = 16 * m + c;
    for (int i = 0; i < 8; ++i) {
      int k = 8 * g + i;
      short e = 0;
      if (k <= 14) e = f2bf(Wc1[(3 + k) * 64 + nu]);
      else if (k == 15) e = f2bf(bc1[nu]);
      else if (k <= 18) e = f2bf(Wc1[(k - 16) * 64 + nu]);
      pk[3072 + m * 512 + l * 8 + i] = e;
    }
  }
  // color GEMM2 A (k-permuted)
  for (int kt = 0; kt < 2; ++kt)
    for (int i = 0; i < 8; ++i) {
      int nu = 32 * kt + 16 * (i >> 2) + 4 * g + (i & 3);
      pk[5120 + kt * 512 + l * 8 + i] = (c < 3) ? f2bf(Wc2[nu * 3 + c]) : (short)0;
    }
}

// ---------------- density pass: MFMA, H entirely in registers ----------------
// Dedicated Xd (no aliasing). Writes geo into Xc rows [xcBase..xcBase+63]
// (16-short rows, col j = density channel j+1, col15 = 1.0). Returns raw sigma.
__device__ __forceinline__ float density_pass(
    const short* __restrict__ pk, short* __restrict__ Xd, short* __restrict__ Xc,
    int lane, int g, int c, float x, float y, float z, float tf, float tLoF,
    const float* __restrict__ bd2g, int xcBase) {
  // 1. pack per-sample input [xh,yh,zh,th | xlo,ylo,zlo,tlo]
  {
    unsigned w0 = cvt2(x, y);
    unsigned w1 = cvt2(z, tf);
    union { unsigned u; float f; } ux, uy, uz;
    ux.u = w0 << 16; uy.u = w0 & 0xFFFF0000u; uz.u = w1 << 16;
    unsigned w2 = cvt2(x - ux.f, y - uy.f);
    unsigned w3 = cvt2(z - uz.f, tLoF);
    u32x4 pv; pv[0] = w0; pv[1] = w1; pv[2] = w2; pv[3] = w3;
    *(u32x4*)&Xd[lane * 8] = pv;
  }
  FENCE;

  bf16x8 A1[4];
#pragma unroll
  for (int m = 0; m < 4; ++m) A1[m] = *(const bf16x8*)(pk + m * 512 + lane * 8);

  // 2. GEMM1 (two m-halves) -> relu -> in-register B-frags P[kt][n][word]
  unsigned P[2][4][4];
#pragma unroll
  for (int mh = 0; mh < 2; ++mh) {
    f32x4 a0[4], a1[4];
#pragma unroll
    for (int n = 0; n < 4; ++n) {
      a0[n] = (f32x4){0.f, 0.f, 0.f, 0.f};
      a1[n] = (f32x4){0.f, 0.f, 0.f, 0.f};
    }
#pragma unroll
    for (int n = 0; n < 4; ++n) {
      bf16x8 v = *(const bf16x8*)&Xd[(16 * n + c) * 8];
      if (g == 1) v[4] = (short)0x3F80;  // bias slot k=12 -> 1.0
      a0[n] = __builtin_amdgcn_mfma_f32_16x16x32_bf16(A1[2 * mh], v, a0[n], 0, 0, 0);
      a1[n] = __builtin_amdgcn_mfma_f32_16x16x32_bf16(A1[2 * mh + 1], v, a1[n], 0, 0, 0);
    }
#pragma unroll
    for (int n = 0; n < 4; ++n) {
      P[mh][n][0] = cvtr(a0[n][0], a0[n][1]);
      P[mh][n][1] = cvtr(a0[n][2], a0[n][3]);
      P[mh][n][2] = cvtr(a1[n][0], a1[n][1]);
      P[mh][n][3] = cvtr(a1[n][2], a1[n][3]);
    }
  }

  // 3. GEMM2 straight from registers (k-permuted A2 matches P layout)
  bf16x8 A2[2];
  A2[0] = *(const bf16x8*)(pk + 2048 + lane * 8);
  A2[1] = *(const bf16x8*)(pk + 2048 + 512 + lane * 8);
  f32x4 o[4];
#pragma unroll
  for (int n = 0; n < 4; ++n) o[n] = (f32x4){0.f, 0.f, 0.f, 0.f};
#pragma unroll
  for (int n = 0; n < 4; ++n)
#pragma unroll
    for (int kt = 0; kt < 2; ++kt)
      o[n] = __builtin_amdgcn_mfma_f32_16x16x32_bf16(
          A2[kt], pack_b(P[kt][n][0], P[kt][n][1], P[kt][n][2], P[kt][n][3]), o[n], 0, 0, 0);

  // 4. epilogue: +bd2; geo -> Xc (channel 4g+j -> col 4g+j-1); sigma via shuffle
  const float4 bd2v = *(const float4*)&bd2g[4 * g];
#pragma unroll
  for (int n = 0; n < 4; ++n) {
    o[n][0] += bd2v.x; o[n][1] += bd2v.y; o[n][2] += bd2v.z; o[n][3] += bd2v.w;
  }
#pragma unroll
  for (int n = 0; n < 4; ++n) {
    short* xr = Xc + (xcBase + 16 * n + c) * 16;
    if (g == 0) {
      *(unsigned*)(xr + 0) = cvt2(o[n][1], o[n][2]);  // cols 0,1 = ch1,ch2
      xr[2] = bf1(o[n][3]);                           // col 2 = ch3
    } else if (g == 1) {
      xr[3] = bf1(o[n][0]);                           // col 3 = ch4
      *(unsigned*)(xr + 4) = cvt2(o[n][1], o[n][2]);  // cols 4,5
      xr[6] = bf1(o[n][3]);                           // col 6
    } else if (g == 2) {
      xr[7] = bf1(o[n][0]);
      *(unsigned*)(xr + 8) = cvt2(o[n][1], o[n][2]);
      xr[10] = bf1(o[n][3]);
    } else {
      xr[11] = bf1(o[n][0]);
      *(unsigned*)(xr + 12) = cvt2(o[n][1], o[n][2]);
      *(unsigned*)(xr + 14) = cvt2(o[n][3], 1.0f);    // col14 = ch15, col15 = 1.0
    }
  }
  FENCE;
  float t0 = __shfl(o[0][0], c);
  float t1 = __shfl(o[1][0], c);
  float t2 = __shfl(o[2][0], c);
  float t3 = __shfl(o[3][0], c);
  return (g == 0) ? t0 : (g == 1) ? t1 : (g == 2) ? t2 : t3;
}

// ---------------- main renderer: 1 ray = 1 wave = 1 block ------------------
__global__ __launch_bounds__(64, 4) void nerf_render(
    const float* __restrict__ rays_o, const float* __restrict__ rays_d,
    const float* __restrict__ time_p, const float* __restrict__ bg,
    const float* __restrict__ bd2g, const float* __restrict__ bc2g,
    const short* __restrict__ pk, float* __restrict__ out) {
  // 7168B shared, disjoint regions (wu aliases cdf+nz after both are dead):
  __shared__ __align__(64) char smem[7168];
  short* Xc  = (short*)smem;            // [0,4096)    128 rows x 32B
  short* Xd  = (short*)(smem + 4096);   // [4096,5120) 64 x 16B  (dedicated)
  float* zsl = (float*)(smem + 5120);   // [5120,5632) 128 f32
  float* ssl = (float*)(smem + 5632);   // [5632,6144) 128 f32
  float* cdfl = (float*)(smem + 6144);  // [6144,6400) 63 f32
  float* nzl  = (float*)(smem + 6400);  // [6400,6656) 64 f32
  float* wul  = (float*)(smem + 6144);  // aliases cdf+nz (dead by then)
  float* wsl  = (float*)(smem + 6656);  // [6656,7168) 128 f32

  const int lane = threadIdx.x;
  const int g = lane >> 4, c = lane & 15;
  const int ray = blockIdx.x;

  const float tf = time_p[0];
  union { unsigned u; float f; } th; th.u = cvt2(tf, tf) << 16;
  const float tLoF = tf - th.f;
  const float o0 = rays_o[ray * 3 + 0], o1 = rays_o[ray * 3 + 1], o2 = rays_o[ray * 3 + 2];
  const float d0 = rays_d[ray * 3 + 0], d1 = rays_d[ray * 3 + 1], d2 = rays_d[ray * 3 + 2];

  // ---- near / far from aabb [-1,1]^3 ----
  float nearv, farv;
  {
    float i0 = fast_rcp((fabsf(d0) < 1e-9f) ? 1e-9f : d0);
    float i1 = fast_rcp((fabsf(d1) < 1e-9f) ? 1e-9f : d1);
    float i2 = fast_rcp((fabsf(d2) < 1e-9f) ? 1e-9f : d2);
    float a0 = (-1.f - o0) * i0, b0 = (1.f - o0) * i0;
    float a1 = (-1.f - o1) * i1, b1 = (1.f - o1) * i1;
    float a2 = (-1.f - o2) * i2, b2 = (1.f - o2) * i2;
    float tmin = fmaxf(fmaxf(fminf(a0, b0), fminf(a1, b1)), fminf(a2, b2));
    float tmax = fminf(fminf(fmaxf(a0, b0), fmaxf(a1, b1)), fmaxf(a2, b2));
    nearv = fmaxf(tmin, 0.05f);
    farv = (tmax < nearv) ? (nearv + 1e-2f) : tmax;
  }
  const float span = farv - nearv;
  const float sd = span * (1.f / 64.f);

  // ---- coarse pass ----
  const float zi = zcoarse(nearv, span, lane);
  float cx = fminf(fmaxf(fmaf(d0, zi, o0), -1.f), 1.f);
  float cy = fminf(fmaxf(fmaf(d1, zi, o1), -1.f), 1.f);
  float cz = fminf(fmaxf(fmaf(d2, zi, o2), -1.f), 1.f);
  float sraw = density_pass(pk, Xd, Xc, lane, g, c, cx, cy, cz, tf, tLoF, bd2g, 0);
  const float sigma = __expf(sraw);

  // ---- coarse compositing -> cdf ----
  const float znext = __shfl_down(zi, 1, 64);
  const float cdelta = (lane < 63) ? (znext - zi) : sd;
  const float calpha = 1.f - __expf(-cdelta * sigma);
  {
    float T = 1.f - calpha + 1e-15f;
    float Pincl = wave_scan_prod(T, lane);
    float Pexcl = __shfl_up(Pincl, 1, 64);
    if (lane == 0) Pexcl = 1.f;
    float wgt = calpha * Pexcl;
    float v = (lane >= 1 && lane <= 62) ? (wgt + 1e-5f) : 0.f;
    float tot = wave_reduce_sum(v);
    float S = wave_scan_sum(v, lane);
    float inv_tot = fast_rcp(tot);
    if (lane < 63) cdfl[lane] = S * inv_tot;
  }
  FENCE;

  // ---- inverse-CDF resampling (bins analytic) ----
  float nzv;
  {
    const float u = ((float)lane + 0.5f) * 0.015625f;
    int lo = 0, hi = 63;
    while (lo < hi) {
      int m = (lo + hi) >> 1;
      if (cdfl[m] <= u) lo = m + 1; else hi = m;
    }
    int below = lo - 1;
    int above = (lo < 62) ? lo : 62;
    float c0 = cdfl[below], c1 = cdfl[above];
    float b0 = 0.5f * (zcoarse(nearv, span, below) + zcoarse(nearv, span, below + 1));
    float b1 = 0.5f * (zcoarse(nearv, span, above) + zcoarse(nearv, span, above + 1));
    float dn = c1 - c0;
    dn = (dn < 1e-5f) ? 1.f : dn;
    nzv = fmaf((u - c0) * fast_rcp(dn), (b1 - b0), b0);
  }
  nzl[lane] = nzv;
  FENCE;

  // ---- fine pass ----
  float fx = fminf(fmaxf(fmaf(d0, nzv, o0), -1.f), 1.f);
  float fy = fminf(fmaxf(fmaf(d1, nzv, o1), -1.f), 1.f);
  float fz = fminf(fmaxf(fmaf(d2, nzv, o2), -1.f), 1.f);
  float nsraw = density_pass(pk, Xd, Xc, lane, g, c, fx, fy, fz, tf, tLoF, bd2g, 64);
  const float nsigma = __expf(nsraw);
  FENCE;

  // ---- stable-merge ranks ----
  int r1, r2;
  {
    int lo = 0, hi = 64;
    while (lo < hi) { int m = (lo + hi) >> 1; if (nzl[m] < zi) lo = m + 1; else hi = m; }
    r1 = lane + lo;
  }
  {
    int lo = 0, hi = 64;
    while (lo < hi) {
      int m = (lo + hi) >> 1;
      if (zcoarse(nearv, span, m) <= nzv) lo = m + 1; else hi = m;
    }
    r2 = lane + lo;
  }
  FENCE;
  zsl[r1] = zi;  ssl[r1] = sigma;
  zsl[r2] = nzv; ssl[r2] = nsigma;
  FENCE;

  // ---- composite over 128 sorted samples ----
  float w0, w1, wsum;
  {
    float z0 = zsl[lane];
    float z0n = zsl[lane + 1];
    float z1 = zsl[lane + 64];
    float dl0 = z0n - z0;
    float dl1 = (lane < 63) ? (zsl[lane + 65] - z1) : sd;
    float al0 = 1.f - __expf(-dl0 * ssl[lane]);
    float al1 = 1.f - __expf(-dl1 * ssl[lane + 64]);
    float T0 = 1.f - al0 + 1e-15f;
    float T1 = 1.f - al1 + 1e-15f;
    float P0 = wave_scan_prod(T0, lane);
    float P1 = wave_scan_prod(T1, lane);
    float prodLo = __shfl(P0, 63, 64);
    float e0 = __shfl_up(P0, 1, 64);
    float e1 = __shfl_up(P1, 1, 64);
    if (lane == 0) { e0 = 1.f; e1 = 1.f; }
    w0 = al0 * e0;
    w1 = al1 * prodLo * e1;
    wsum = wave_reduce_sum(w0 + w1);
    wsl[lane] = w0;
    wsl[lane + 64] = w1;
  }
  FENCE;

  // ---- weights back in unmerged order ----
  const float wc = wsl[r1];
  const float wf = wsl[r2];
  FENCE;
  wul[lane] = wc;
  wul[64 + lane] = wf;
  const unsigned long long mC = __ballot(wc > 1e-4f);
  const unsigned long long mF = __ballot(wf > 1e-4f);
  FENCE;

  // ---- color MLP: H in registers, dir from registers on g>=2 lanes ----
  bf16x8 CA[4];
#pragma unroll
  for (int m = 0; m < 4; ++m) CA[m] = *(const bf16x8*)(pk + 3072 + m * 512 + lane * 8);
  bf16x8 C2A[2];
  C2A[0] = *(const bf16x8*)(pk + 5120 + lane * 8);
  C2A[1] = *(const bf16x8*)(pk + 5120 + 512 + lane * 8);
  const float bc20 = bc2g[0], bc21 = bc2g[1], bc22 = bc2g[2];
  const bf16x8 bD = pack_b(cvt2(d0, d1), cvt2(d2, 0.f), 0u, 0u);
  const int xoffs = (g < 2) ? 8 * g : 0;

  float cr = 0.f, cgr = 0.f, cb = 0.f;
#pragma unroll
  for (int half = 0; half < 2; ++half) {
    const unsigned long long mm = half ? mF : mC;
#pragma unroll
    for (int n = 0; n < 4; ++n) {
      if ((mm >> (16 * n)) & 0xFFFFull) {
        bf16x8 ld = *(const bf16x8*)&Xc[(64 * half + 16 * n + c) * 16 + xoffs];
        bf16x8 V = (g < 2) ? ld : bD;
        f32x4 a[4];
#pragma unroll
        for (int m = 0; m < 4; ++m) {
          a[m] = (f32x4){0.f, 0.f, 0.f, 0.f};
          a[m] = __builtin_amdgcn_mfma_f32_16x16x32_bf16(CA[m], V, a[m], 0, 0, 0);
        }
        f32x4 oc = (f32x4){0.f, 0.f, 0.f, 0.f};
#pragma unroll
        for (int kt = 0; kt < 2; ++kt) {
          bf16x8 Bh = pack_b(cvtr(a[2 * kt][0], a[2 * kt][1]),
                             cvtr(a[2 * kt][2], a[2 * kt][3]),
                             cvtr(a[2 * kt + 1][0], a[2 * kt + 1][1]),
                             cvtr(a[2 * kt + 1][2], a[2 * kt + 1][3]));
          oc = __builtin_amdgcn_mfma_f32_16x16x32_bf16(C2A[kt], Bh, oc, 0, 0, 0);
        }
        if (g == 0) {
          float wgt = wul[64 * half + 16 * n + c];
          if (wgt > 1e-4f) {
            cr  += wgt * fast_rcp(1.f + __expf(-(oc[0] + bc20)));
            cgr += wgt * fast_rcp(1.f + __expf(-(oc[1] + bc21)));
            cb  += wgt * fast_rcp(1.f + __expf(-(oc[2] + bc22)));
          }
        }
      }
    }
  }

  cr = wave_reduce_sum(cr);
  cgr = wave_reduce_sum(cgr);
  cb = wave_reduce_sum(cb);

  if (lane == 0) {
    const float rem = 1.f - wsum;
    out[ray * 3 + 0] = cr + rem * bg[0];
    out[ray * 3 + 1] = cgr + rem * bg[1];
    out[ray * 3 + 2] = cb + rem * bg[2];
  }
}

extern "C" void kernel_launch(void* const* d_in, const int* in_sizes, int n_in,
                              void* d_out, int out_size, void* d_ws, size_t ws_size,
                              hipStream_t stream) {
  const float* rays_o = (const float*)d_in[0];
  const float* rays_d = (const float*)d_in[1];
  const float* time_p = (const float*)d_in[2];
  const float* bg     = (const float*)d_in[3];
  const float* Wd1    = (const float*)d_in[4];
  const float* bd1    = (const float*)d_in[5];
  const float* Wd2    = (const float*)d_in[6];
  const float* bd2    = (const float*)d_in[7];
  const float* Wc1    = (const float*)d_in[8];
  const float* bc1    = (const float*)d_in[9];
  const float* Wc2    = (const float*)d_in[10];
  const float* bc2    = (const float*)d_in[11];

  short* pk = (short*)d_ws;  // 12 KiB packed weight fragments
  pack_weights<<<1, 64, 0, stream>>>(Wd1, bd1, Wd2, Wc1, bc1, Wc2, pk);
  nerf_render<<<NRAYS, 64, 0, stream>>>(rays_o, rays_d, time_p, bg, bd2, bc2, pk,
                                        (float*)d_out);
}

// Round 7
// 39.080 us; speedup vs baseline: 2.5123x; 1.1335x over previous
//
#include <hip/hip_runtime.h>
#include <math.h>

#define NRAYS 8192

typedef __attribute__((ext_vector_type(8))) short bf16x8;
typedef __attribute__((ext_vector_type(4))) float f32x4;
typedef __attribute__((ext_vector_type(4))) unsigned u32x4;

#define FENCE asm volatile("" ::: "memory")

__device__ __forceinline__ short f2bf(float f) {
  union { float f; unsigned u; } v; v.f = f;
  unsigned r = (v.u + 0x7FFFu + ((v.u >> 16) & 1u)) >> 16;
  return (short)r;
}
__device__ __forceinline__ float bf2f(short s) {
  union { unsigned u; float f; } v; v.u = ((unsigned)(unsigned short)s) << 16;
  return v.f;
}
// HW packed f32->bf16 (RNE): dst = {lo=bf16(a), hi=bf16(b)}
__device__ __forceinline__ unsigned cvt2(float a, float b) {
  unsigned r;
  asm("v_cvt_pk_bf16_f32 %0, %1, %2" : "=v"(r) : "v"(a), "v"(b));
  return r;
}
__device__ __forceinline__ unsigned cvtr(float a, float b) {  // relu + pack
  return cvt2(fmaxf(a, 0.f), fmaxf(b, 0.f));
}
__device__ __forceinline__ float fast_rcp(float x) {
  float r;
  asm("v_rcp_f32 %0, %1" : "=v"(r) : "v"(x));
  return r;
}
__device__ __forceinline__ bf16x8 pack_b(unsigned a, unsigned b, unsigned c, unsigned d) {
  union { u32x4 u; bf16x8 v; } x;
  x.u = (u32x4){a, b, c, d};
  return x.v;
}
__device__ __forceinline__ float readlane63(float v) {
  return __int_as_float(__builtin_amdgcn_readlane(__float_as_int(v), 63));
}
// coarse z formula — single definition (bit-exact reuse everywhere)
__device__ __forceinline__ float zcoarse(float nearv, float span, int m) {
  return fmaf(span, (float)m * (1.f / 63.f), nearv);
}

// ------------- DPP wave64 primitives via update_dpp (compiler-managed hazards)
// update_dpp(old, src, ctrl, row_mask, bank_mask, bound_ctrl=false):
// masked/invalid lanes yield `old` (the identity), others the DPP-moved src.
#define UPD(OLD, SRC, CTRL, RMASK)                                        \
  __int_as_float(__builtin_amdgcn_update_dpp(                             \
      __float_as_int(OLD), __float_as_int(SRC), CTRL, RMASK, 0xf, false))

__device__ __forceinline__ float scan_mul_dpp(float v) {
  v *= UPD(1.f, v, 0x111, 0xf);  // row_shr:1
  v *= UPD(1.f, v, 0x112, 0xf);  // row_shr:2
  v *= UPD(1.f, v, 0x114, 0xf);  // row_shr:4
  v *= UPD(1.f, v, 0x118, 0xf);  // row_shr:8
  v *= UPD(1.f, v, 0x142, 0xa);  // row_bcast:15 -> rows 1,3
  v *= UPD(1.f, v, 0x143, 0xc);  // row_bcast:31 -> rows 2,3
  return v;
}
__device__ __forceinline__ float scan_add_dpp(float v) {
  v += UPD(0.f, v, 0x111, 0xf);
  v += UPD(0.f, v, 0x112, 0xf);
  v += UPD(0.f, v, 0x114, 0xf);
  v += UPD(0.f, v, 0x118, 0xf);
  v += UPD(0.f, v, 0x142, 0xa);
  v += UPD(0.f, v, 0x143, 0xc);
  return v;
}
// Reduction: butterfly within rows, then cross-row bcast; total on lane 63.
__device__ __forceinline__ float red_add_dpp(float v) {
  v += UPD(0.f, v, 0xB1, 0xf);   // quad_perm [1,0,3,2]
  v += UPD(0.f, v, 0x4E, 0xf);   // quad_perm [2,3,0,1]
  v += UPD(0.f, v, 0x141, 0xf);  // row_half_mirror
  v += UPD(0.f, v, 0x140, 0xf);  // row_mirror
  v += UPD(0.f, v, 0x142, 0xa);  // row_bcast:15
  v += UPD(0.f, v, 0x143, 0xc);  // row_bcast:31
  return v;  // full sum valid on lane 63
}

// ---------------- weight fragment packing (64 threads) ----------------------
// pk (shorts): A1 @0 [4m][64][8] | A2 @2048 [2kt][64][8] | CA @3072 [4m][64][8]
//              C2A @5120 [2kt][64][8]
// GEMM2 A-frags use k-permutation: elem (kt,g,i) <-> nu = 32kt+16(i>>2)+4g+(i&3)
// Color GEMM1 k-map: k0=sigma(ignored,0) k1-15=geo ch1-15 (Wc1 rows 3..17),
//                    k16-18=dir (Wc1 rows 0..2), k19=bc1, k>=20: 0
__global__ void pack_weights(const float* __restrict__ Wd1, const float* __restrict__ bd1,
                             const float* __restrict__ Wd2, const float* __restrict__ Wc1,
                             const float* __restrict__ bc1, const float* __restrict__ Wc2,
                             short* __restrict__ pk) {
  const int l = threadIdx.x;  // 64 threads
  const int g = l >> 4, c = l & 15;
  // density GEMM1 A: xvec = [xh,yh,zh,th | xlo,ylo,zlo,tlo], g1 slot4 = bias (B=1.0)
  for (int m = 0; m < 4; ++m) {
    int nu = 16 * m + c;
    short e[8] = {0, 0, 0, 0, 0, 0, 0, 0};
    if (g == 0) {
      for (int i = 0; i < 4; ++i) {
        short h = f2bf(Wd1[i * 64 + nu]);
        e[i] = h;
        e[4 + i] = h;
      }
    } else if (g == 1) {
      for (int i = 0; i < 4; ++i) {
        float w = Wd1[i * 64 + nu];
        e[i] = f2bf(w - bf2f(f2bf(w)));
      }
      e[4] = f2bf(bd1[nu]);
    }
    for (int i = 0; i < 8; ++i) pk[m * 512 + l * 8 + i] = e[i];
  }
  // density GEMM2 A (k-permuted)
  for (int kt = 0; kt < 2; ++kt)
    for (int i = 0; i < 8; ++i) {
      int nu = 32 * kt + 16 * (i >> 2) + 4 * g + (i & 3);
      pk[2048 + kt * 512 + l * 8 + i] = f2bf(Wd2[nu * 16 + c]);
    }
  // color GEMM1 A
  for (int m = 0; m < 4; ++m) {
    int nu = 16 * m + c;
    for (int i = 0; i < 8; ++i) {
      int k = 8 * g + i;
      short e = 0;
      if (k >= 1 && k <= 15) e = f2bf(Wc1[(2 + k) * 64 + nu]);
      else if (k >= 16 && k <= 18) e = f2bf(Wc1[(k - 16) * 64 + nu]);
      else if (k == 19) e = f2bf(bc1[nu]);
      pk[3072 + m * 512 + l * 8 + i] = e;
    }
  }
  // color GEMM2 A (k-permuted)
  for (int kt = 0; kt < 2; ++kt)
    for (int i = 0; i < 8; ++i) {
      int nu = 32 * kt + 16 * (i >> 2) + 4 * g + (i & 3);
      pk[5120 + kt * 512 + l * 8 + i] = (c < 3) ? f2bf(Wc2[nu * 3 + c]) : (short)0;
    }
}

// ---------------- density pass: MFMA, H entirely in registers ----------------
// Writes channels 4g..4g+3 to Xc cols 4g..4g+3 (branch-free, aligned b32 x2).
// Returns raw sigma (channel 0) for the owning lane.
__device__ __forceinline__ float density_pass(
    const short* __restrict__ pk, short* __restrict__ Xd, short* __restrict__ Xc,
    int lane, int g, int c, float x, float y, float z, float tf, float tLoF,
    const float* __restrict__ bd2g, int xcBase) {
  // 1. pack per-sample input [xh,yh,zh,th | xlo,ylo,zlo,tlo]
  {
    unsigned w0 = cvt2(x, y);
    unsigned w1 = cvt2(z, tf);
    union { unsigned u; float f; } ux, uy, uz;
    ux.u = w0 << 16; uy.u = w0 & 0xFFFF0000u; uz.u = w1 << 16;
    unsigned w2 = cvt2(x - ux.f, y - uy.f);
    unsigned w3 = cvt2(z - uz.f, tLoF);
    u32x4 pv; pv[0] = w0; pv[1] = w1; pv[2] = w2; pv[3] = w3;
    *(u32x4*)&Xd[lane * 8] = pv;
  }
  FENCE;

  bf16x8 A1[4];
#pragma unroll
  for (int m = 0; m < 4; ++m) A1[m] = *(const bf16x8*)(pk + m * 512 + lane * 8);

  // 2. GEMM1 (two m-halves) -> relu -> in-register B-frags P[kt][n][word]
  unsigned P[2][4][4];
#pragma unroll
  for (int mh = 0; mh < 2; ++mh) {
    f32x4 a0[4], a1[4];
#pragma unroll
    for (int n = 0; n < 4; ++n) {
      a0[n] = (f32x4){0.f, 0.f, 0.f, 0.f};
      a1[n] = (f32x4){0.f, 0.f, 0.f, 0.f};
    }
#pragma unroll
    for (int n = 0; n < 4; ++n) {
      bf16x8 v = *(const bf16x8*)&Xd[(16 * n + c) * 8];
      if (g == 1) v[4] = (short)0x3F80;  // bias slot k=12 -> 1.0
      a0[n] = __builtin_amdgcn_mfma_f32_16x16x32_bf16(A1[2 * mh], v, a0[n], 0, 0, 0);
      a1[n] = __builtin_amdgcn_mfma_f32_16x16x32_bf16(A1[2 * mh + 1], v, a1[n], 0, 0, 0);
    }
#pragma unroll
    for (int n = 0; n < 4; ++n) {
      P[mh][n][0] = cvtr(a0[n][0], a0[n][1]);
      P[mh][n][1] = cvtr(a0[n][2], a0[n][3]);
      P[mh][n][2] = cvtr(a1[n][0], a1[n][1]);
      P[mh][n][3] = cvtr(a1[n][2], a1[n][3]);
    }
  }

  // 3. GEMM2 straight from registers (k-permuted A2 matches P layout)
  bf16x8 A2[2];
  A2[0] = *(const bf16x8*)(pk + 2048 + lane * 8);
  A2[1] = *(const bf16x8*)(pk + 2048 + 512 + lane * 8);
  f32x4 o[4];
#pragma unroll
  for (int n = 0; n < 4; ++n) o[n] = (f32x4){0.f, 0.f, 0.f, 0.f};
#pragma unroll
  for (int n = 0; n < 4; ++n)
#pragma unroll
    for (int kt = 0; kt < 2; ++kt)
      o[n] = __builtin_amdgcn_mfma_f32_16x16x32_bf16(
          A2[kt], pack_b(P[kt][n][0], P[kt][n][1], P[kt][n][2], P[kt][n][3]), o[n], 0, 0, 0);

  // 4. epilogue: +bd2; channels 4g..4g+3 -> cols 4g..4g+3 (uniform, aligned)
  const float4 bd2v = *(const float4*)&bd2g[4 * g];
#pragma unroll
  for (int n = 0; n < 4; ++n) {
    o[n][0] += bd2v.x; o[n][1] += bd2v.y; o[n][2] += bd2v.z; o[n][3] += bd2v.w;
  }
#pragma unroll
  for (int n = 0; n < 4; ++n) {
    short* xr = Xc + (xcBase + 16 * n + c) * 16 + 4 * g;
    *(unsigned*)(xr + 0) = cvt2(o[n][0], o[n][1]);
    *(unsigned*)(xr + 2) = cvt2(o[n][2], o[n][3]);
  }
  FENCE;
  float t0 = __shfl(o[0][0], c);
  float t1 = __shfl(o[1][0], c);
  float t2 = __shfl(o[2][0], c);
  float t3 = __shfl(o[3][0], c);
  return (g == 0) ? t0 : (g == 1) ? t1 : (g == 2) ? t2 : t3;
}

// ---------------- main renderer: 1 ray = 1 wave = 1 block ------------------
__global__ __launch_bounds__(64, 4) void nerf_render(
    const float* __restrict__ rays_o, const float* __restrict__ rays_d,
    const float* __restrict__ time_p, const float* __restrict__ bg,
    const float* __restrict__ bd2g, const float* __restrict__ bc2g,
    const short* __restrict__ pk, float* __restrict__ out) {
  __shared__ __align__(64) char smem[7168];
  short* Xc  = (short*)smem;            // [0,4096)    128 rows x 32B
  short* Xd  = (short*)(smem + 4096);   // [4096,5120) 64 x 16B
  float* zsl = (float*)(smem + 5120);   // [5120,5632) 128 f32
  float* ssl = (float*)(smem + 5632);   // [5632,6144) 128 f32
  float* cdfl = (float*)(smem + 6144);  // [6144,6400) 63 f32
  float* nzl  = (float*)(smem + 6400);  // [6400,6656) 64 f32
  float* wul  = (float*)(smem + 6144);  // aliases cdf+nz (dead by then)
  float* wsl  = (float*)(smem + 6656);  // [6656,7168) 128 f32

  const int lane = threadIdx.x;
  const int g = lane >> 4, c = lane & 15;
  const int ray = blockIdx.x;

  const float tf = time_p[0];
  union { unsigned u; float f; } th; th.u = cvt2(tf, tf) << 16;
  const float tLoF = tf - th.f;
  const float o0 = rays_o[ray * 3 + 0], o1 = rays_o[ray * 3 + 1], o2 = rays_o[ray * 3 + 2];
  const float d0 = rays_d[ray * 3 + 0], d1 = rays_d[ray * 3 + 1], d2 = rays_d[ray * 3 + 2];

  // ---- near / far from aabb [-1,1]^3 ----
  float nearv, farv;
  {
    float i0 = fast_rcp((fabsf(d0) < 1e-9f) ? 1e-9f : d0);
    float i1 = fast_rcp((fabsf(d1) < 1e-9f) ? 1e-9f : d1);
    float i2 = fast_rcp((fabsf(d2) < 1e-9f) ? 1e-9f : d2);
    float a0 = (-1.f - o0) * i0, b0 = (1.f - o0) * i0;
    float a1 = (-1.f - o1) * i1, b1 = (1.f - o1) * i1;
    float a2 = (-1.f - o2) * i2, b2 = (1.f - o2) * i2;
    float tmin = fmaxf(fmaxf(fminf(a0, b0), fminf(a1, b1)), fminf(a2, b2));
    float tmax = fminf(fminf(fmaxf(a0, b0), fmaxf(a1, b1)), fmaxf(a2, b2));
    nearv = fmaxf(tmin, 0.05f);
    farv = (tmax < nearv) ? (nearv + 1e-2f) : tmax;
  }
  const float span = farv - nearv;
  const float sd = span * (1.f / 64.f);

  // ---- coarse pass ----
  const float zi = zcoarse(nearv, span, lane);
  float cx = fminf(fmaxf(fmaf(d0, zi, o0), -1.f), 1.f);
  float cy = fminf(fmaxf(fmaf(d1, zi, o1), -1.f), 1.f);
  float cz = fminf(fmaxf(fmaf(d2, zi, o2), -1.f), 1.f);
  float sraw = density_pass(pk, Xd, Xc, lane, g, c, cx, cy, cz, tf, tLoF, bd2g, 0);
  const float sigma = __expf(sraw);

  // ---- coarse compositing -> cdf (DPP scans) ----
  const float znext = __shfl_down(zi, 1, 64);
  const float cdelta = (lane < 63) ? (znext - zi) : sd;
  const float calpha = 1.f - __expf(-cdelta * sigma);
  {
    float T = 1.f - calpha + 1e-15f;
    float Pincl = scan_mul_dpp(T);
    float Pexcl = __shfl_up(Pincl, 1, 64);
    if (lane == 0) Pexcl = 1.f;
    float wgt = calpha * Pexcl;
    float v = (lane >= 1 && lane <= 62) ? (wgt + 1e-5f) : 0.f;
    float S = scan_add_dpp(v);
    float inv_tot = fast_rcp(readlane63(S));  // total = inclusive scan @ lane63
    if (lane < 63) cdfl[lane] = S * inv_tot;
  }
  FENCE;

  // ---- inverse-CDF resampling (bins analytic) ----
  float nzv;
  {
    const float u = ((float)lane + 0.5f) * 0.015625f;
    int lo = 0, hi = 63;
    while (lo < hi) {
      int m = (lo + hi) >> 1;
      if (cdfl[m] <= u) lo = m + 1; else hi = m;
    }
    int below = lo - 1;
    int above = (lo < 62) ? lo : 62;
    float c0 = cdfl[below], c1 = cdfl[above];
    float b0 = 0.5f * (zcoarse(nearv, span, below) + zcoarse(nearv, span, below + 1));
    float b1 = 0.5f * (zcoarse(nearv, span, above) + zcoarse(nearv, span, above + 1));
    float dn = c1 - c0;
    dn = (dn < 1e-5f) ? 1.f : dn;
    nzv = fmaf((u - c0) * fast_rcp(dn), (b1 - b0), b0);
  }
  nzl[lane] = nzv;
  FENCE;

  // ---- fine pass ----
  float fx = fminf(fmaxf(fmaf(d0, nzv, o0), -1.f), 1.f);
  float fy = fminf(fmaxf(fmaf(d1, nzv, o1), -1.f), 1.f);
  float fz = fminf(fmaxf(fmaf(d2, nzv, o2), -1.f), 1.f);
  float nsraw = density_pass(pk, Xd, Xc, lane, g, c, fx, fy, fz, tf, tLoF, bd2g, 64);
  const float nsigma = __expf(nsraw);
  FENCE;

  // ---- stable-merge ranks ----
  int r1, r2;
  {
    int lo = 0, hi = 64;
    while (lo < hi) { int m = (lo + hi) >> 1; if (nzl[m] < zi) lo = m + 1; else hi = m; }
    r1 = lane + lo;
  }
  {
    int lo = 0, hi = 64;
    while (lo < hi) {
      int m = (lo + hi) >> 1;
      if (zcoarse(nearv, span, m) <= nzv) lo = m + 1; else hi = m;
    }
    r2 = lane + lo;
  }
  FENCE;
  zsl[r1] = zi;  ssl[r1] = sigma;
  zsl[r2] = nzv; ssl[r2] = nsigma;
  FENCE;

  // ---- composite over 128 sorted samples (DPP scans) ----
  float w0, w1, wsum;
  {
    float z0 = zsl[lane];
    float z0n = zsl[lane + 1];
    float z1 = zsl[lane + 64];
    float dl0 = z0n - z0;
    float dl1 = (lane < 63) ? (zsl[lane + 65] - z1) : sd;
    float al0 = 1.f - __expf(-dl0 * ssl[lane]);
    float al1 = 1.f - __expf(-dl1 * ssl[lane + 64]);
    float T0 = 1.f - al0 + 1e-15f;
    float T1 = 1.f - al1 + 1e-15f;
    float P0 = scan_mul_dpp(T0);
    float P1 = scan_mul_dpp(T1);
    float prodLo = readlane63(P0);
    float e0 = __shfl_up(P0, 1, 64);
    float e1 = __shfl_up(P1, 1, 64);
    if (lane == 0) { e0 = 1.f; e1 = 1.f; }
    w0 = al0 * e0;
    w1 = al1 * prodLo * e1;
    wsum = red_add_dpp(w0 + w1);  // valid on lane 63
    wsl[lane] = w0;
    wsl[lane + 64] = w1;
  }
  FENCE;

  // ---- weights back in unmerged order ----
  const float wc = wsl[r1];
  const float wf = wsl[r2];
  FENCE;
  wul[lane] = wc;
  wul[64 + lane] = wf;
  const unsigned long long mC = __ballot(wc > 1e-4f);
  const unsigned long long mF = __ballot(wf > 1e-4f);
  FENCE;

  // ---- color MLP: H in registers; dir+bias from g==2 register operand ----
  bf16x8 CA[4];
#pragma unroll
  for (int m = 0; m < 4; ++m) CA[m] = *(const bf16x8*)(pk + 3072 + m * 512 + lane * 8);
  bf16x8 C2A[2];
  C2A[0] = *(const bf16x8*)(pk + 5120 + lane * 8);
  C2A[1] = *(const bf16x8*)(pk + 5120 + 512 + lane * 8);
  const float bc20 = bc2g[0], bc21 = bc2g[1], bc22 = bc2g[2];
  const bf16x8 bD = pack_b(cvt2(d0, d1), cvt2(d2, 1.0f), 0u, 0u);  // k16-19: d,1.0
  const bf16x8 bZ = pack_b(0u, 0u, 0u, 0u);
  const int xoffs = (g < 2) ? 8 * g : 0;

  float cr = 0.f, cgr = 0.f, cb = 0.f;
#pragma unroll
  for (int half = 0; half < 2; ++half) {
    const unsigned long long mm = half ? mF : mC;
#pragma unroll
    for (int n = 0; n < 4; ++n) {
      if ((mm >> (16 * n)) & 0xFFFFull) {
        bf16x8 ld = *(const bf16x8*)&Xc[(64 * half + 16 * n + c) * 16 + xoffs];
        bf16x8 V = (g < 2) ? ld : ((g == 2) ? bD : bZ);
        f32x4 a[4];
#pragma unroll
        for (int m = 0; m < 4; ++m) {
          a[m] = (f32x4){0.f, 0.f, 0.f, 0.f};
          a[m] = __builtin_amdgcn_mfma_f32_16x16x32_bf16(CA[m], V, a[m], 0, 0, 0);
        }
        f32x4 oc = (f32x4){0.f, 0.f, 0.f, 0.f};
#pragma unroll
        for (int kt = 0; kt < 2; ++kt) {
          bf16x8 Bh = pack_b(cvtr(a[2 * kt][0], a[2 * kt][1]),
                             cvtr(a[2 * kt][2], a[2 * kt][3]),
                             cvtr(a[2 * kt + 1][0], a[2 * kt + 1][1]),
                             cvtr(a[2 * kt + 1][2], a[2 * kt + 1][3]));
          oc = __builtin_amdgcn_mfma_f32_16x16x32_bf16(C2A[kt], Bh, oc, 0, 0, 0);
        }
        if (g == 0) {
          float wgt = wul[64 * half + 16 * n + c];
          if (wgt > 1e-4f) {
            cr  += wgt * fast_rcp(1.f + __expf(-(oc[0] + bc20)));
            cgr += wgt * fast_rcp(1.f + __expf(-(oc[1] + bc21)));
            cb  += wgt * fast_rcp(1.f + __expf(-(oc[2] + bc22)));
          }
        }
      }
    }
  }

  cr = red_add_dpp(cr);
  cgr = red_add_dpp(cgr);
  cb = red_add_dpp(cb);

  if (lane == 63) {  // reductions land on lane 63
    const float rem = 1.f - wsum;
    out[ray * 3 + 0] = cr + rem * bg[0];
    out[ray * 3 + 1] = cgr + rem * bg[1];
    out[ray * 3 + 2] = cb + rem * bg[2];
  }
}

extern "C" void kernel_launch(void* const* d_in, const int* in_sizes, int n_in,
                              void* d_out, int out_size, void* d_ws, size_t ws_size,
                              hipStream_t stream) {
  const float* rays_o = (const float*)d_in[0];
  const float* rays_d = (const float*)d_in[1];
  const float* time_p = (const float*)d_in[2];
  const float* bg     = (const float*)d_in[3];
  const float* Wd1    = (const float*)d_in[4];
  const float* bd1    = (const float*)d_in[5];
  const float* Wd2    = (const float*)d_in[6];
  const float* bd2    = (const float*)d_in[7];
  const float* Wc1    = (const float*)d_in[8];
  const float* bc1    = (const float*)d_in[9];
  const float* Wc2    = (const float*)d_in[10];
  const float* bc2    = (const float*)d_in[11];

  short* pk = (short*)d_ws;  // 12 KiB packed weight fragments
  pack_weights<<<1, 64, 0, stream>>>(Wd1, bd1, Wd2, Wc1, bc1, Wc2, pk);
  nerf_render<<<NRAYS, 64, 0, stream>>>(rays_o, rays_d, time_p, bg, bd2, bc2, pk,
                                        (float*)d_out);
}